// Round 1
// baseline (6153.492 us; speedup 1.0000x reference)
//
#include <hip/hip_runtime.h>
#include <hip/hip_bf16.h>

// ---------------------------------------------------------------------------
// EdgePredModel: NodeMLP + 2x GATv2 + EdgeMLP, full fp32.
// Sizes fixed per reference.
// ---------------------------------------------------------------------------
constexpr int N_NODES = 20000;
constexpr int N_EDGES = 320000;
constexpr int NBLK    = (N_NODES + 255) / 256;   // 79 (scan blocks)

__device__ __forceinline__ float lrelu(float x) { return x > 0.f ? x : 0.2f * x; }

// ------------------------------ CSR build ---------------------------------
__global__ void hist_kernel(const int* __restrict__ dst, int* __restrict__ counts) {
    int e = blockIdx.x * 256 + threadIdx.x;
    if (e < N_EDGES) atomicAdd(&counts[dst[e]], 1);
}

__global__ void scan1_kernel(const int* __restrict__ counts, int* __restrict__ partial,
                             int* __restrict__ bsum) {
    __shared__ int s[256];
    int i = blockIdx.x * 256 + threadIdx.x;
    int v = (i < N_NODES) ? counts[i] : 0;
    s[threadIdx.x] = v;
    __syncthreads();
    for (int off = 1; off < 256; off <<= 1) {
        int t = (threadIdx.x >= off) ? s[threadIdx.x - off] : 0;
        __syncthreads();
        s[threadIdx.x] += t;
        __syncthreads();
    }
    if (i < N_NODES) partial[i] = s[threadIdx.x] - v;     // exclusive within block
    if (threadIdx.x == 255) bsum[blockIdx.x] = s[255];    // block total
}

__global__ void scan2_kernel(int* __restrict__ bsum) {
    __shared__ int s[128];
    int b = threadIdx.x;
    int v = (b < NBLK) ? bsum[b] : 0;
    s[b] = v;
    __syncthreads();
    for (int off = 1; off < 128; off <<= 1) {
        int t = (b >= off) ? s[b - off] : 0;
        __syncthreads();
        s[b] += t;
        __syncthreads();
    }
    if (b < NBLK) bsum[128 + b] = s[b] - v;               // exclusive block offsets
}

__global__ void scan3_kernel(int* __restrict__ row_off, const int* __restrict__ bsum,
                             int* __restrict__ cursor) {
    int i = blockIdx.x * 256 + threadIdx.x;
    if (i < N_NODES) {
        int v = row_off[i] + bsum[128 + blockIdx.x];
        row_off[i] = v;
        cursor[i]  = v;
    }
    if (i == 0) row_off[N_NODES] = N_EDGES;
}

__global__ void scatter_kernel(const int* __restrict__ dst, int* __restrict__ cursor,
                               int* __restrict__ eidx) {
    int e = blockIdx.x * 256 + threadIdx.x;
    if (e < N_EDGES) {
        int p = atomicAdd(&cursor[dst[e]], 1);
        eidx[p] = e;
    }
}

// ------------------------------ dense linear -------------------------------
// Y[n][j] = act(b[j] + sum_k X[n][k] * W[k][j]); blockDim.x == M; grid = N/NPB.
template <int K, int M, int NPB, bool RELU>
__global__ void linear_kernel(const float* __restrict__ X, const float* __restrict__ W,
                              const float* __restrict__ bias, float* __restrict__ Y,
                              int N) {
    __shared__ float Xs[NPB * K];
    const int tid = threadIdx.x;
    const int n0  = blockIdx.x * NPB;
    for (int idx = tid; idx < NPB * K; idx += M)
        Xs[idx] = X[n0 * K + idx];          // rows contiguous: X[(n0+nn)*K+k]
    __syncthreads();
    float acc[NPB];
    const float bj = bias[tid];
#pragma unroll
    for (int nn = 0; nn < NPB; ++nn) acc[nn] = bj;
    for (int k = 0; k < K; k += 4) {
        float wv0 = W[(k + 0) * M + tid];
        float wv1 = W[(k + 1) * M + tid];
        float wv2 = W[(k + 2) * M + tid];
        float wv3 = W[(k + 3) * M + tid];
#pragma unroll
        for (int nn = 0; nn < NPB; ++nn) {
            const float4 x4 = *reinterpret_cast<const float4*>(&Xs[nn * K + k]);
            acc[nn] = fmaf(x4.x, wv0, acc[nn]);
            acc[nn] = fmaf(x4.y, wv1, acc[nn]);
            acc[nn] = fmaf(x4.z, wv2, acc[nn]);
            acc[nn] = fmaf(x4.w, wv3, acc[nn]);
        }
    }
#pragma unroll
    for (int nn = 0; nn < NPB; ++nn) {
        float v = acc[nn];
        if (RELU) v = fmaxf(v, 0.f);
        Y[(n0 + nn) * M + tid] = v;
    }
}

// ------------------------------ GATv2 pieces -------------------------------
// One wave per edge; both heads. fs/fd are (N,256) = (N, H*D) with H=2, D=128.
__global__ void gat_logits_kernel(const float* __restrict__ fs, const float* __restrict__ fd,
                                  const float* __restrict__ attn, const int* __restrict__ src,
                                  const int* __restrict__ dst, float* __restrict__ logits) {
    const int wave = threadIdx.x >> 6;
    const int lane = threadIdx.x & 63;
    const int e = blockIdx.x * 4 + wave;
    if (e >= N_EDGES) return;
    const int s = src[e], d = dst[e];
    const float4 a  = *reinterpret_cast<const float4*>(&fs[s * 256 + lane * 4]);
    const float4 b  = *reinterpret_cast<const float4*>(&fd[d * 256 + lane * 4]);
    const float4 at = *reinterpret_cast<const float4*>(&attn[lane * 4]);
    float p = lrelu(a.x + b.x) * at.x;
    p = fmaf(lrelu(a.y + b.y), at.y, p);
    p = fmaf(lrelu(a.z + b.z), at.z, p);
    p = fmaf(lrelu(a.w + b.w), at.w, p);
    // reduce within each 32-lane half (head 0 = lanes 0..31, head 1 = 32..63)
    for (int off = 1; off < 32; off <<= 1) p += __shfl_xor(p, off);
    if ((lane & 31) == 0) logits[e * 2 + (lane >> 5)] = p;
}

// One wave per (node, head): segment softmax + weighted sum of fs[src], then relu.
__global__ void gat_agg_kernel(const float* __restrict__ fs, const float* __restrict__ logits,
                               const int* __restrict__ eidx, const int* __restrict__ row_off,
                               const int* __restrict__ src, float* __restrict__ out) {
    const int wave = threadIdx.x >> 6;
    const int lane = threadIdx.x & 63;
    const int id = blockIdx.x * 4 + wave;          // id in [0, N_NODES*2)
    const int n = id >> 1, h = id & 1;
    const int s0 = row_off[n], s1 = row_off[n + 1];
    float m = -INFINITY;
    for (int i = s0; i < s1; ++i) m = fmaxf(m, logits[eidx[i] * 2 + h]);
    float ssum = 0.f, a0 = 0.f, a1 = 0.f;
    for (int i = s0; i < s1; ++i) {
        const int e = eidx[i];
        const float w = __expf(logits[e * 2 + h] - m);
        ssum += w;
        const float2 v = *reinterpret_cast<const float2*>(
            &fs[src[e] * 256 + h * 128 + lane * 2]);
        a0 = fmaf(w, v.x, a0);
        a1 = fmaf(w, v.y, a1);
    }
    const float inv = (s1 > s0) ? 1.f / ssum : 0.f;
    out[n * 256 + h * 128 + lane * 2]     = fmaxf(a0 * inv, 0.f);
    out[n * 256 + h * 128 + lane * 2 + 1] = fmaxf(a1 * inv, 0.f);
}

// ------------------------------ fused EdgeMLP ------------------------------
// Per block: 32 edges. X = [h1[src](128) | h1[dst](128) | g2o[src](256) | g2o[dst](256)]
// layer0: 768->512 (+relu, to LDS), layer1: 512->256 (+relu, to LDS), layer2: 256->1.
// LDS: exactly 64 KB. Activations stored transposed [j][e] (e contiguous).
__global__ __launch_bounds__(256, 2) void edge_mlp_kernel(
    const float* __restrict__ h1, const float* __restrict__ g2o,
    const int* __restrict__ src, const int* __restrict__ dst,
    const float* __restrict__ w0, const float* __restrict__ b0,
    const float* __restrict__ w1, const float* __restrict__ b1,
    const float* __restrict__ w2, const float* __restrict__ b2,
    float* __restrict__ out) {
    __shared__ float smem[16384];                  // 64 KB
    const int tid = threadIdx.x;
    const int e0  = blockIdx.x * 32;

    // gather roles: thread (ge, kq) loads 4 consecutive k for edge ge
    const int ge = tid >> 3;                        // 0..31
    const int kq = tid & 7;                         // 0..7
    const int gs = src[e0 + ge];
    const int gd = dst[e0 + ge];

    // compute roles: 4 edges x 8 outs per thread
    const int jg = tid & 31;                        // 32 j-groups
    const int eg = tid >> 5;                        // 8 e-groups
    const int j0 = jg * 8;
    const int ce = eg * 4;

    float acc[4][8];

    // ---------------- layer 0: K=768, out-chunks of 256 ----------------
    for (int oc = 0; oc < 2; ++oc) {
        const int jb = oc * 256;
        float* Xs = &smem[oc * 8192];               // 1024 floats used, aliased into c0 region
#pragma unroll
        for (int jj = 0; jj < 8; ++jj) {
            const float bj = b0[jb + j0 + jj];
#pragma unroll
            for (int ee = 0; ee < 4; ++ee) acc[ee][jj] = bj;
        }
        for (int kc = 0; kc < 24; ++kc) {
            const int k0 = kc * 32;
            __syncthreads();                        // previous chunk's Xs reads done
            const int k = k0 + kq * 4;
            float4 v;
            if (k < 128)       v = *reinterpret_cast<const float4*>(&h1[gs * 128 + k]);
            else if (k < 256)  v = *reinterpret_cast<const float4*>(&h1[gd * 128 + (k - 128)]);
            else if (k < 512)  v = *reinterpret_cast<const float4*>(&g2o[gs * 256 + (k - 256)]);
            else               v = *reinterpret_cast<const float4*>(&g2o[gd * 256 + (k - 512)]);
            const int kb = kq * 4;
            Xs[(kb + 0) * 32 + ge] = v.x;
            Xs[(kb + 1) * 32 + ge] = v.y;
            Xs[(kb + 2) * 32 + ge] = v.z;
            Xs[(kb + 3) * 32 + ge] = v.w;
            __syncthreads();
#pragma unroll
            for (int kk = 0; kk < 32; ++kk) {
                const float4 xv = *reinterpret_cast<const float4*>(&Xs[kk * 32 + ce]);
                const float* wr = &w0[(k0 + kk) * 512 + jb + j0];
                const float4 wa = *reinterpret_cast<const float4*>(wr);
                const float4 wb = *reinterpret_cast<const float4*>(wr + 4);
                const float xs[4] = {xv.x, xv.y, xv.z, xv.w};
                const float ws[8] = {wa.x, wa.y, wa.z, wa.w, wb.x, wb.y, wb.z, wb.w};
#pragma unroll
                for (int ee = 0; ee < 4; ++ee)
#pragma unroll
                    for (int jj = 0; jj < 8; ++jj)
                        acc[ee][jj] = fmaf(xs[ee], ws[jj], acc[ee][jj]);
            }
        }
        __syncthreads();                            // Xs reads done before c0 overwrite
#pragma unroll
        for (int jj = 0; jj < 8; ++jj) {
            float4 o;
            o.x = fmaxf(acc[0][jj], 0.f);
            o.y = fmaxf(acc[1][jj], 0.f);
            o.z = fmaxf(acc[2][jj], 0.f);
            o.w = fmaxf(acc[3][jj], 0.f);
            *reinterpret_cast<float4*>(&smem[(jb + j0 + jj) * 32 + ce]) = o;
        }
    }
    __syncthreads();

    // ---------------- layer 1: K=512 -> 256 outs ----------------
    float acc1[4][8];
#pragma unroll
    for (int jj = 0; jj < 8; ++jj) {
        const float bj = b1[j0 + jj];
#pragma unroll
        for (int ee = 0; ee < 4; ++ee) acc1[ee][jj] = bj;
    }
    for (int k = 0; k < 512; ++k) {
        const float4 xv = *reinterpret_cast<const float4*>(&smem[k * 32 + ce]);
        const float* wr = &w1[k * 256 + j0];
        const float4 wa = *reinterpret_cast<const float4*>(wr);
        const float4 wb = *reinterpret_cast<const float4*>(wr + 4);
        const float xs[4] = {xv.x, xv.y, xv.z, xv.w};
        const float ws[8] = {wa.x, wa.y, wa.z, wa.w, wb.x, wb.y, wb.z, wb.w};
#pragma unroll
        for (int ee = 0; ee < 4; ++ee)
#pragma unroll
            for (int jj = 0; jj < 8; ++jj)
                acc1[ee][jj] = fmaf(xs[ee], ws[jj], acc1[ee][jj]);
    }
    __syncthreads();                                // all c0 reads done
#pragma unroll
    for (int jj = 0; jj < 8; ++jj) {
        float4 o;
        o.x = fmaxf(acc1[0][jj], 0.f);
        o.y = fmaxf(acc1[1][jj], 0.f);
        o.z = fmaxf(acc1[2][jj], 0.f);
        o.w = fmaxf(acc1[3][jj], 0.f);
        *reinterpret_cast<float4*>(&smem[(j0 + jj) * 32 + ce]) = o;   // c1 in region A
    }
    __syncthreads();

    // ---------------- layer 2: 256 -> 1 ----------------
    const int le = tid & 31, kg = tid >> 5;
    float p = 0.f;
#pragma unroll
    for (int kk = 0; kk < 32; ++kk) {
        const int k = kg * 32 + kk;
        p = fmaf(smem[k * 32 + le], w2[k], p);
    }
    smem[8192 + kg * 32 + le] = p;                  // region B (dead c0 area)
    __syncthreads();
    if (tid < 32) {
        float s = b2[0];
#pragma unroll
        for (int g = 0; g < 8; ++g) s += smem[8192 + g * 32 + tid];
        out[e0 + tid] = s;
    }
}

// ------------------------------ launch ------------------------------------
extern "C" void kernel_launch(void* const* d_in, const int* in_sizes, int n_in,
                              void* d_out, int out_size, void* d_ws, size_t ws_size,
                              hipStream_t stream) {
    (void)in_sizes; (void)n_in; (void)out_size; (void)ws_size;
    const float* x    = (const float*)d_in[0];
    const int*   src  = (const int*)d_in[1];
    const int*   dst  = (const int*)d_in[2];
    const float* nw0  = (const float*)d_in[3];
    const float* nb0  = (const float*)d_in[4];
    const float* nw1  = (const float*)d_in[5];
    const float* nb1  = (const float*)d_in[6];
    const float* g1ws = (const float*)d_in[7];
    const float* g1bs = (const float*)d_in[8];
    const float* g1wd = (const float*)d_in[9];
    const float* g1bd = (const float*)d_in[10];
    const float* g1a  = (const float*)d_in[11];
    const float* g2ws = (const float*)d_in[12];
    const float* g2bs = (const float*)d_in[13];
    const float* g2wd = (const float*)d_in[14];
    const float* g2bd = (const float*)d_in[15];
    const float* g2a  = (const float*)d_in[16];
    const float* ew0  = (const float*)d_in[17];
    const float* eb0  = (const float*)d_in[18];
    const float* ew1  = (const float*)d_in[19];
    const float* eb1  = (const float*)d_in[20];
    const float* ew2  = (const float*)d_in[21];
    const float* eb2  = (const float*)d_in[22];
    float* out = (float*)d_out;

    // workspace layout (floats then ints); total ~96.2 MB
    float* wsF  = (float*)d_ws;
    float* h1   = wsF;                      // 20000*128
    float* fsb  = wsF + 2560000;            // 20000*256
    float* fdb  = wsF + 7680000;            // 20000*256
    float* g1o  = wsF + 12800000;           // 20000*256
    float* g2o  = wsF + 17920000;           // 20000*256
    float* lg   = wsF + 23040000;           // 320000*2
    int* wsI     = (int*)(wsF + 23680000);
    int* row_off = wsI;                     // 20001 (padded to 20016)
    int* cursor  = wsI + 20016;             // 20000 (counts, then scatter cursors)
    int* eidx    = wsI + 40016;             // 320000
    int* bsum    = wsI + 360016;            // 256

    // ---- CSR build (edges grouped by dst) ----
    hipMemsetAsync(cursor, 0, N_NODES * sizeof(int), stream);
    hist_kernel<<<1250, 256, 0, stream>>>(dst, cursor);
    scan1_kernel<<<NBLK, 256, 0, stream>>>(cursor, row_off, bsum);
    scan2_kernel<<<1, 128, 0, stream>>>(bsum);
    scan3_kernel<<<NBLK, 256, 0, stream>>>(row_off, bsum, cursor);
    scatter_kernel<<<1250, 256, 0, stream>>>(dst, cursor, eidx);

    // ---- NodeMLP: h1 = relu(relu(x@nw0+nb0)@nw1+nb1) ----
    linear_kernel<64, 128, 8, true><<<2500, 128, 0, stream>>>(x, nw0, nb0, fsb, N_NODES);
    linear_kernel<128, 128, 8, true><<<2500, 128, 0, stream>>>(fsb, nw1, nb1, h1, N_NODES);

    // ---- GATv2 layer 1 (in=64 -> 2x128) ----
    linear_kernel<64, 256, 8, false><<<2500, 256, 0, stream>>>(x, g1ws, g1bs, fsb, N_NODES);
    linear_kernel<64, 256, 8, false><<<2500, 256, 0, stream>>>(x, g1wd, g1bd, fdb, N_NODES);
    gat_logits_kernel<<<N_EDGES / 4, 256, 0, stream>>>(fsb, fdb, g1a, src, dst, lg);
    gat_agg_kernel<<<N_NODES * 2 / 4, 256, 0, stream>>>(fsb, lg, eidx, row_off, src, g1o);

    // ---- GATv2 layer 2 (in=256 -> 2x128) ----
    linear_kernel<256, 256, 8, false><<<2500, 256, 0, stream>>>(g1o, g2ws, g2bs, fsb, N_NODES);
    linear_kernel<256, 256, 8, false><<<2500, 256, 0, stream>>>(g1o, g2wd, g2bd, fdb, N_NODES);
    gat_logits_kernel<<<N_EDGES / 4, 256, 0, stream>>>(fsb, fdb, g2a, src, dst, lg);
    gat_agg_kernel<<<N_NODES * 2 / 4, 256, 0, stream>>>(fsb, lg, eidx, row_off, src, g2o);

    // ---- fused EdgeMLP: (E,768) -> 512 -> 256 -> 1 ----
    edge_mlp_kernel<<<N_EDGES / 32, 256, 0, stream>>>(h1, g2o, src, dst,
                                                      ew0, eb0, ew1, eb1, ew2, eb2, out);
}

// Round 2
// 2042.571 us; speedup vs baseline: 3.0126x; 3.0126x over previous
//
#include <hip/hip_runtime.h>
#include <hip/hip_bf16.h>

// ---------------------------------------------------------------------------
// EdgePredModel: NodeMLP + 2x GATv2 + EdgeMLP, full fp32.
// R2: EdgeMLP layer-0 decomposed into per-node S/D precompute (16x FLOP cut);
//     new conflict-free edge kernel (layer1 + folded layer2).
// ---------------------------------------------------------------------------
constexpr int N_NODES = 20000;
constexpr int N_EDGES = 320000;
constexpr int NBLK    = (N_NODES + 255) / 256;   // 79 (scan blocks)

__device__ __forceinline__ float lrelu(float x) { return x > 0.f ? x : 0.2f * x; }

// ------------------------------ CSR build ---------------------------------
__global__ void hist_kernel(const int* __restrict__ dst, int* __restrict__ counts) {
    int e = blockIdx.x * 256 + threadIdx.x;
    if (e < N_EDGES) atomicAdd(&counts[dst[e]], 1);
}

__global__ void scan1_kernel(const int* __restrict__ counts, int* __restrict__ partial,
                             int* __restrict__ bsum) {
    __shared__ int s[256];
    int i = blockIdx.x * 256 + threadIdx.x;
    int v = (i < N_NODES) ? counts[i] : 0;
    s[threadIdx.x] = v;
    __syncthreads();
    for (int off = 1; off < 256; off <<= 1) {
        int t = (threadIdx.x >= off) ? s[threadIdx.x - off] : 0;
        __syncthreads();
        s[threadIdx.x] += t;
        __syncthreads();
    }
    if (i < N_NODES) partial[i] = s[threadIdx.x] - v;     // exclusive within block
    if (threadIdx.x == 255) bsum[blockIdx.x] = s[255];    // block total
}

__global__ void scan2_kernel(int* __restrict__ bsum) {
    __shared__ int s[128];
    int b = threadIdx.x;
    int v = (b < NBLK) ? bsum[b] : 0;
    s[b] = v;
    __syncthreads();
    for (int off = 1; off < 128; off <<= 1) {
        int t = (b >= off) ? s[b - off] : 0;
        __syncthreads();
        s[b] += t;
        __syncthreads();
    }
    if (b < NBLK) bsum[128 + b] = s[b] - v;               // exclusive block offsets
}

__global__ void scan3_kernel(int* __restrict__ row_off, const int* __restrict__ bsum,
                             int* __restrict__ cursor) {
    int i = blockIdx.x * 256 + threadIdx.x;
    if (i < N_NODES) {
        int v = row_off[i] + bsum[128 + blockIdx.x];
        row_off[i] = v;
        cursor[i]  = v;
    }
    if (i == 0) row_off[N_NODES] = N_EDGES;
}

__global__ void scatter_kernel(const int* __restrict__ dst, int* __restrict__ cursor,
                               int* __restrict__ eidx) {
    int e = blockIdx.x * 256 + threadIdx.x;
    if (e < N_EDGES) {
        int p = atomicAdd(&cursor[dst[e]], 1);
        eidx[p] = e;
    }
}

// ------------------------------ dense linear -------------------------------
// Y[n][j] = act(b[j] + sum_k X[n][k] * W[k][j]); blockDim.x == M; grid = N/NPB.
template <int K, int M, int NPB, bool RELU>
__global__ void linear_kernel(const float* __restrict__ X, const float* __restrict__ W,
                              const float* __restrict__ bias, float* __restrict__ Y,
                              int N) {
    __shared__ float Xs[NPB * K];
    const int tid = threadIdx.x;
    const int n0  = blockIdx.x * NPB;
    for (int idx = tid; idx < NPB * K; idx += M)
        Xs[idx] = X[n0 * K + idx];          // rows contiguous: X[(n0+nn)*K+k]
    __syncthreads();
    float acc[NPB];
    const float bj = bias[tid];
#pragma unroll
    for (int nn = 0; nn < NPB; ++nn) acc[nn] = bj;
    for (int k = 0; k < K; k += 4) {
        float wv0 = W[(k + 0) * M + tid];
        float wv1 = W[(k + 1) * M + tid];
        float wv2 = W[(k + 2) * M + tid];
        float wv3 = W[(k + 3) * M + tid];
#pragma unroll
        for (int nn = 0; nn < NPB; ++nn) {
            const float4 x4 = *reinterpret_cast<const float4*>(&Xs[nn * K + k]);
            acc[nn] = fmaf(x4.x, wv0, acc[nn]);
            acc[nn] = fmaf(x4.y, wv1, acc[nn]);
            acc[nn] = fmaf(x4.z, wv2, acc[nn]);
            acc[nn] = fmaf(x4.w, wv3, acc[nn]);
        }
    }
#pragma unroll
    for (int nn = 0; nn < NPB; ++nn) {
        float v = acc[nn];
        if (RELU) v = fmaxf(v, 0.f);
        Y[(n0 + nn) * M + tid] = v;
    }
}

// -------------------- S/D precompute for EdgeMLP layer-0 -------------------
// Y[n][j] = (bias?) + sum_{k<128} h1[n][k]*W0[r1+k][j] + sum_{k<256} g2o[n][k]*W0[r2+k][j]
// blockDim = 512 (=M), NPB nodes per block.
template <bool HASB>
__global__ void linear_sd_kernel(const float* __restrict__ X1,  // (N,128)
                                 const float* __restrict__ X2,  // (N,256)
                                 const float* __restrict__ W0,  // (768,512)
                                 int r1, int r2,
                                 const float* __restrict__ bias,
                                 float* __restrict__ Y) {       // (N,512)
    constexpr int NPB = 16;
    __shared__ float Xs[NPB * 384];
    const int tid = threadIdx.x;
    const int n0  = blockIdx.x * NPB;
    for (int idx = tid; idx < NPB * 384; idx += 512) {
        const int nn = idx / 384, k = idx - nn * 384;
        Xs[idx] = (k < 128) ? X1[(n0 + nn) * 128 + k]
                            : X2[(n0 + nn) * 256 + (k - 128)];
    }
    __syncthreads();
    float acc[NPB];
    const float bj = HASB ? bias[tid] : 0.f;
#pragma unroll
    for (int nn = 0; nn < NPB; ++nn) acc[nn] = bj;
    for (int k = 0; k < 384; k += 4) {
        const int row = (k < 128) ? (r1 + k) : (r2 + k - 128);  // quads never straddle
        const float* Wk = W0 + (size_t)row * 512 + tid;
        const float wv0 = Wk[0];
        const float wv1 = Wk[512];
        const float wv2 = Wk[1024];
        const float wv3 = Wk[1536];
#pragma unroll
        for (int nn = 0; nn < NPB; ++nn) {
            const float4 x4 = *reinterpret_cast<const float4*>(&Xs[nn * 384 + k]);
            acc[nn] = fmaf(x4.x, wv0, acc[nn]);
            acc[nn] = fmaf(x4.y, wv1, acc[nn]);
            acc[nn] = fmaf(x4.z, wv2, acc[nn]);
            acc[nn] = fmaf(x4.w, wv3, acc[nn]);
        }
    }
#pragma unroll
    for (int nn = 0; nn < NPB; ++nn) Y[(size_t)(n0 + nn) * 512 + tid] = acc[nn];
}

// ------------------------------ GATv2 pieces -------------------------------
__global__ void gat_logits_kernel(const float* __restrict__ fs, const float* __restrict__ fd,
                                  const float* __restrict__ attn, const int* __restrict__ src,
                                  const int* __restrict__ dst, float* __restrict__ logits) {
    const int wave = threadIdx.x >> 6;
    const int lane = threadIdx.x & 63;
    const int e = blockIdx.x * 4 + wave;
    if (e >= N_EDGES) return;
    const int s = src[e], d = dst[e];
    const float4 a  = *reinterpret_cast<const float4*>(&fs[s * 256 + lane * 4]);
    const float4 b  = *reinterpret_cast<const float4*>(&fd[d * 256 + lane * 4]);
    const float4 at = *reinterpret_cast<const float4*>(&attn[lane * 4]);
    float p = lrelu(a.x + b.x) * at.x;
    p = fmaf(lrelu(a.y + b.y), at.y, p);
    p = fmaf(lrelu(a.z + b.z), at.z, p);
    p = fmaf(lrelu(a.w + b.w), at.w, p);
    for (int off = 1; off < 32; off <<= 1) p += __shfl_xor(p, off);
    if ((lane & 31) == 0) logits[e * 2 + (lane >> 5)] = p;
}

__global__ void gat_agg_kernel(const float* __restrict__ fs, const float* __restrict__ logits,
                               const int* __restrict__ eidx, const int* __restrict__ row_off,
                               const int* __restrict__ src, float* __restrict__ out) {
    const int wave = threadIdx.x >> 6;
    const int lane = threadIdx.x & 63;
    const int id = blockIdx.x * 4 + wave;          // id in [0, N_NODES*2)
    const int n = id >> 1, h = id & 1;
    const int s0 = row_off[n], s1 = row_off[n + 1];
    float m = -INFINITY;
    for (int i = s0; i < s1; ++i) m = fmaxf(m, logits[eidx[i] * 2 + h]);
    float ssum = 0.f, a0 = 0.f, a1 = 0.f;
    for (int i = s0; i < s1; ++i) {
        const int e = eidx[i];
        const float w = __expf(logits[e * 2 + h] - m);
        ssum += w;
        const float2 v = *reinterpret_cast<const float2*>(
            &fs[src[e] * 256 + h * 128 + lane * 2]);
        a0 = fmaf(w, v.x, a0);
        a1 = fmaf(w, v.y, a1);
    }
    const float inv = (s1 > s0) ? 1.f / ssum : 0.f;
    out[n * 256 + h * 128 + lane * 2]     = fmaxf(a0 * inv, 0.f);
    out[n * 256 + h * 128 + lane * 2 + 1] = fmaxf(a1 * inv, 0.f);
}

// ------------------------------ fused EdgeMLP ------------------------------
// Per block: 64 edges. x = relu(S[src] + D[dst]) (512), staged in 128-k chunks.
// layer1 (512->256) accumulated in registers; layer2 (256->1) folded into a
// per-thread partial + wave shuffle-reduce. No conflicted LDS patterns:
//  - staging writes: [k][e] layout, row stride 68 -> 2 lanes/bank (free)
//  - compute reads: wave-broadcast (all 64 lanes same address)
__global__ __launch_bounds__(256, 4) void edge_mlp2_kernel(
    const float* __restrict__ S, const float* __restrict__ Dn,
    const int* __restrict__ src, const int* __restrict__ dst,
    const float* __restrict__ w1, const float* __restrict__ b1,
    const float* __restrict__ w2, const float* __restrict__ b2,
    float* __restrict__ out) {
    __shared__ float Xs[128 * 68];                 // 34816 B
    const int tid = threadIdx.x;
    const int e0  = blockIdx.x * 64;

    // staging roles: 4 lanes per edge, 64B contiguous per edge per load
    const int ge = tid >> 2;                        // 0..63 edge
    const int kq = tid & 3;                         // 0..3
    const int gs = src[e0 + ge];
    const int gd = dst[e0 + ge];
    const float* Srow = S  + (size_t)gs * 512;
    const float* Drow = Dn + (size_t)gd * 512;

    // compute roles: 4 j x 16 e per thread; wave w owns edges 16w..16w+15
    const int j0 = (tid & 63) * 4;
    const int ce = (tid >> 6) * 16;

    float acc[4][16];
#pragma unroll
    for (int jj = 0; jj < 4; ++jj) {
        const float bv = b1[j0 + jj];
#pragma unroll
        for (int ee = 0; ee < 16; ++ee) acc[jj][ee] = bv;
    }

    for (int c = 0; c < 4; ++c) {
        const int kb = c * 128;
        __syncthreads();                            // prior chunk's reads done
#pragma unroll
        for (int i = 0; i < 8; ++i) {
            const int k = kq * 4 + i * 16;          // within chunk
            const float4 a = *reinterpret_cast<const float4*>(Srow + kb + k);
            const float4 b = *reinterpret_cast<const float4*>(Drow + kb + k);
            float* p = &Xs[k * 68 + ge];
            p[0]   = fmaxf(a.x + b.x, 0.f);
            p[68]  = fmaxf(a.y + b.y, 0.f);
            p[136] = fmaxf(a.z + b.z, 0.f);
            p[204] = fmaxf(a.w + b.w, 0.f);
        }
        __syncthreads();
#pragma unroll 2
        for (int k = 0; k < 128; ++k) {
            const float4 w = *reinterpret_cast<const float4*>(
                &w1[(size_t)(kb + k) * 256 + j0]);
            const float* xr = &Xs[k * 68 + ce];
            const float4 x0 = *reinterpret_cast<const float4*>(xr);
            const float4 x1 = *reinterpret_cast<const float4*>(xr + 4);
            const float4 x2 = *reinterpret_cast<const float4*>(xr + 8);
            const float4 x3 = *reinterpret_cast<const float4*>(xr + 12);
            const float xs[16] = {x0.x, x0.y, x0.z, x0.w, x1.x, x1.y, x1.z, x1.w,
                                  x2.x, x2.y, x2.z, x2.w, x3.x, x3.y, x3.z, x3.w};
            const float ws[4] = {w.x, w.y, w.z, w.w};
#pragma unroll
            for (int jj = 0; jj < 4; ++jj)
#pragma unroll
                for (int ee = 0; ee < 16; ++ee)
                    acc[jj][ee] = fmaf(xs[ee], ws[jj], acc[jj][ee]);
        }
    }

    // layer 2 folded: part[ee] = sum_j relu(y_je) * w2[j], reduce over 64 j-groups
    const float4 w2v = *reinterpret_cast<const float4*>(&w2[j0]);
    const float w2s[4] = {w2v.x, w2v.y, w2v.z, w2v.w};
    float part[16];
#pragma unroll
    for (int ee = 0; ee < 16; ++ee) {
        float p = 0.f;
#pragma unroll
        for (int jj = 0; jj < 4; ++jj)
            p = fmaf(fmaxf(acc[jj][ee], 0.f), w2s[jj], p);
        part[ee] = p;
    }
#pragma unroll
    for (int off = 1; off < 64; off <<= 1)
#pragma unroll
        for (int ee = 0; ee < 16; ++ee) part[ee] += __shfl_xor(part[ee], off);
    if ((tid & 63) == 0) {
        const float b2v = b2[0];
#pragma unroll
        for (int ee = 0; ee < 16; ++ee) out[e0 + ce + ee] = part[ee] + b2v;
    }
}

// ------------------------------ launch ------------------------------------
extern "C" void kernel_launch(void* const* d_in, const int* in_sizes, int n_in,
                              void* d_out, int out_size, void* d_ws, size_t ws_size,
                              hipStream_t stream) {
    (void)in_sizes; (void)n_in; (void)out_size; (void)ws_size;
    const float* x    = (const float*)d_in[0];
    const int*   src  = (const int*)d_in[1];
    const int*   dst  = (const int*)d_in[2];
    const float* nw0  = (const float*)d_in[3];
    const float* nb0  = (const float*)d_in[4];
    const float* nw1  = (const float*)d_in[5];
    const float* nb1  = (const float*)d_in[6];
    const float* g1ws = (const float*)d_in[7];
    const float* g1bs = (const float*)d_in[8];
    const float* g1wd = (const float*)d_in[9];
    const float* g1bd = (const float*)d_in[10];
    const float* g1a  = (const float*)d_in[11];
    const float* g2ws = (const float*)d_in[12];
    const float* g2bs = (const float*)d_in[13];
    const float* g2wd = (const float*)d_in[14];
    const float* g2bd = (const float*)d_in[15];
    const float* g2a  = (const float*)d_in[16];
    const float* ew0  = (const float*)d_in[17];
    const float* eb0  = (const float*)d_in[18];
    const float* ew1  = (const float*)d_in[19];
    const float* eb1  = (const float*)d_in[20];
    const float* ew2  = (const float*)d_in[21];
    const float* eb2  = (const float*)d_in[22];
    float* out = (float*)d_out;

    // workspace layout (floats), ~114 MB total:
    // h1[0,2.56M) g2o[2.56M,7.68M) fsb[7.68M,12.8M) fdb[12.8M,17.92M)
    // g1o[17.92M,23.04M) lg[23.04M,23.68M)
    // S overlays fsb+fdb after they're dead; D at [17.92M.. wait, g1o is S/D-
    // independent too — D goes at [17.92M+...]: see below. ints at the end.
    float* wsF = (float*)d_ws;
    float* h1  = wsF;                       // 20000*128          [0, 2.56M)
    float* g2o = wsF + 2560000;             // 20000*256          [2.56M, 7.68M)
    float* fsb = wsF + 7680000;             // 20000*256          [7.68M, 12.8M)
    float* fdb = wsF + 12800000;            // 20000*256          [12.8M, 17.92M)
    float* g1o = wsF + 17920000;            // 20000*256          [17.92M, 23.04M)
    float* lg  = wsF + 23040000;            // 320000*2           [23.04M, 23.68M)
    float* Sb  = wsF + 7680000;             // 20000*512 overlays fsb+fdb (dead by then)
    float* Db  = wsF + 17920000;            // 20000*512 overlays g1o+lg (dead by then)
    int* wsI     = (int*)(wsF + 28160000);
    int* row_off = wsI;                     // 20001 (padded to 20016)
    int* cursor  = wsI + 20016;             // 20000
    int* eidx    = wsI + 40016;             // 320000
    int* bsum    = wsI + 360016;            // 256

    // ---- CSR build (edges grouped by dst) ----
    hipMemsetAsync(cursor, 0, N_NODES * sizeof(int), stream);
    hist_kernel<<<1250, 256, 0, stream>>>(dst, cursor);
    scan1_kernel<<<NBLK, 256, 0, stream>>>(cursor, row_off, bsum);
    scan2_kernel<<<1, 128, 0, stream>>>(bsum);
    scan3_kernel<<<NBLK, 256, 0, stream>>>(row_off, bsum, cursor);
    scatter_kernel<<<1250, 256, 0, stream>>>(dst, cursor, eidx);

    // ---- NodeMLP: h1 = relu(relu(x@nw0+nb0)@nw1+nb1) ----
    linear_kernel<64, 128, 8, true><<<2500, 128, 0, stream>>>(x, nw0, nb0, fsb, N_NODES);
    linear_kernel<128, 128, 8, true><<<2500, 128, 0, stream>>>(fsb, nw1, nb1, h1, N_NODES);

    // ---- GATv2 layer 1 (in=64 -> 2x128) ----
    linear_kernel<64, 256, 8, false><<<2500, 256, 0, stream>>>(x, g1ws, g1bs, fsb, N_NODES);
    linear_kernel<64, 256, 8, false><<<2500, 256, 0, stream>>>(x, g1wd, g1bd, fdb, N_NODES);
    gat_logits_kernel<<<N_EDGES / 4, 256, 0, stream>>>(fsb, fdb, g1a, src, dst, lg);
    gat_agg_kernel<<<N_NODES * 2 / 4, 256, 0, stream>>>(fsb, lg, eidx, row_off, src, g1o);

    // ---- GATv2 layer 2 (in=256 -> 2x128) ----
    linear_kernel<256, 256, 8, false><<<2500, 256, 0, stream>>>(g1o, g2ws, g2bs, fsb, N_NODES);
    linear_kernel<256, 256, 8, false><<<2500, 256, 0, stream>>>(g1o, g2wd, g2bd, fdb, N_NODES);
    gat_logits_kernel<<<N_EDGES / 4, 256, 0, stream>>>(fsb, fdb, g2a, src, dst, lg);
    gat_agg_kernel<<<N_NODES * 2 / 4, 256, 0, stream>>>(fsb, lg, eidx, row_off, src, g2o);
    // fsb/fdb, g1o, lg are dead from here on.

    // ---- S/D precompute (EdgeMLP layer-0 decomposition) ----
    // S = h1@W0[0:128] + g2o@W0[256:512]; D = h1@W0[128:256] + g2o@W0[512:768] + b0
    linear_sd_kernel<false><<<1250, 512, 0, stream>>>(h1, g2o, ew0, 0, 256, nullptr, Sb);
    linear_sd_kernel<true><<<1250, 512, 0, stream>>>(h1, g2o, ew0, 128, 512, eb0, Db);

    // ---- fused EdgeMLP: relu(S[src]+D[dst]) -> 512x256 -> relu -> 256x1 ----
    edge_mlp2_kernel<<<N_EDGES / 64, 256, 0, stream>>>(Sb, Db, src, dst,
                                                       ew1, eb1, ew2, eb2, out);
}

// Round 3
// 1520.944 us; speedup vs baseline: 4.0458x; 1.3430x over previous
//
#include <hip/hip_runtime.h>
#include <hip/hip_bf16.h>

// ---------------------------------------------------------------------------
// EdgePredModel: NodeMLP + 2x GATv2 + EdgeMLP.
// R3: EdgeMLP layer-1 (512x256 per-edge GEMM) via split-fp16 MFMA
//     (32x32x16_f16, 3-product emulation of fp32), W1 prepacked into
//     B-fragment order; A-fragments built in registers (no LDS main loop).
// ---------------------------------------------------------------------------
constexpr int N_NODES = 20000;
constexpr int N_EDGES = 320000;
constexpr int NBLK    = (N_NODES + 255) / 256;   // 79 (scan blocks)

typedef _Float16 half8 __attribute__((ext_vector_type(8)));
typedef float    f32x16 __attribute__((ext_vector_type(16)));

__device__ __forceinline__ float lrelu(float x) { return x > 0.f ? x : 0.2f * x; }

// ------------------------------ CSR build ---------------------------------
__global__ void hist_kernel(const int* __restrict__ dst, int* __restrict__ counts) {
    int e = blockIdx.x * 256 + threadIdx.x;
    if (e < N_EDGES) atomicAdd(&counts[dst[e]], 1);
}

__global__ void scan1_kernel(const int* __restrict__ counts, int* __restrict__ partial,
                             int* __restrict__ bsum) {
    __shared__ int s[256];
    int i = blockIdx.x * 256 + threadIdx.x;
    int v = (i < N_NODES) ? counts[i] : 0;
    s[threadIdx.x] = v;
    __syncthreads();
    for (int off = 1; off < 256; off <<= 1) {
        int t = (threadIdx.x >= off) ? s[threadIdx.x - off] : 0;
        __syncthreads();
        s[threadIdx.x] += t;
        __syncthreads();
    }
    if (i < N_NODES) partial[i] = s[threadIdx.x] - v;     // exclusive within block
    if (threadIdx.x == 255) bsum[blockIdx.x] = s[255];    // block total
}

__global__ void scan2_kernel(int* __restrict__ bsum) {
    __shared__ int s[128];
    int b = threadIdx.x;
    int v = (b < NBLK) ? bsum[b] : 0;
    s[b] = v;
    __syncthreads();
    for (int off = 1; off < 128; off <<= 1) {
        int t = (b >= off) ? s[b - off] : 0;
        __syncthreads();
        s[b] += t;
        __syncthreads();
    }
    if (b < NBLK) bsum[128 + b] = s[b] - v;               // exclusive block offsets
}

__global__ void scan3_kernel(int* __restrict__ row_off, const int* __restrict__ bsum,
                             int* __restrict__ cursor) {
    int i = blockIdx.x * 256 + threadIdx.x;
    if (i < N_NODES) {
        int v = row_off[i] + bsum[128 + blockIdx.x];
        row_off[i] = v;
        cursor[i]  = v;
    }
    if (i == 0) row_off[N_NODES] = N_EDGES;
}

__global__ void scatter_kernel(const int* __restrict__ dst, int* __restrict__ cursor,
                               int* __restrict__ eidx) {
    int e = blockIdx.x * 256 + threadIdx.x;
    if (e < N_EDGES) {
        int p = atomicAdd(&cursor[dst[e]], 1);
        eidx[p] = e;
    }
}

// ------------------------------ dense linear -------------------------------
template <int K, int M, int NPB, bool RELU>
__global__ void linear_kernel(const float* __restrict__ X, const float* __restrict__ W,
                              const float* __restrict__ bias, float* __restrict__ Y,
                              int N) {
    __shared__ float Xs[NPB * K];
    const int tid = threadIdx.x;
    const int n0  = blockIdx.x * NPB;
    for (int idx = tid; idx < NPB * K; idx += M)
        Xs[idx] = X[n0 * K + idx];
    __syncthreads();
    float acc[NPB];
    const float bj = bias[tid];
#pragma unroll
    for (int nn = 0; nn < NPB; ++nn) acc[nn] = bj;
    for (int k = 0; k < K; k += 4) {
        float wv0 = W[(k + 0) * M + tid];
        float wv1 = W[(k + 1) * M + tid];
        float wv2 = W[(k + 2) * M + tid];
        float wv3 = W[(k + 3) * M + tid];
#pragma unroll
        for (int nn = 0; nn < NPB; ++nn) {
            const float4 x4 = *reinterpret_cast<const float4*>(&Xs[nn * K + k]);
            acc[nn] = fmaf(x4.x, wv0, acc[nn]);
            acc[nn] = fmaf(x4.y, wv1, acc[nn]);
            acc[nn] = fmaf(x4.z, wv2, acc[nn]);
            acc[nn] = fmaf(x4.w, wv3, acc[nn]);
        }
    }
#pragma unroll
    for (int nn = 0; nn < NPB; ++nn) {
        float v = acc[nn];
        if (RELU) v = fmaxf(v, 0.f);
        Y[(n0 + nn) * M + tid] = v;
    }
}

// -------------------- S/D precompute for EdgeMLP layer-0 -------------------
template <bool HASB>
__global__ void linear_sd_kernel(const float* __restrict__ X1,  // (N,128)
                                 const float* __restrict__ X2,  // (N,256)
                                 const float* __restrict__ W0,  // (768,512)
                                 int r1, int r2,
                                 const float* __restrict__ bias,
                                 float* __restrict__ Y) {       // (N,512)
    constexpr int NPB = 16;
    __shared__ float Xs[NPB * 384];
    const int tid = threadIdx.x;
    const int n0  = blockIdx.x * NPB;
    for (int idx = tid; idx < NPB * 384; idx += 512) {
        const int nn = idx / 384, k = idx - nn * 384;
        Xs[idx] = (k < 128) ? X1[(n0 + nn) * 128 + k]
                            : X2[(n0 + nn) * 256 + (k - 128)];
    }
    __syncthreads();
    float acc[NPB];
    const float bj = HASB ? bias[tid] : 0.f;
#pragma unroll
    for (int nn = 0; nn < NPB; ++nn) acc[nn] = bj;
    for (int k = 0; k < 384; k += 4) {
        const int row = (k < 128) ? (r1 + k) : (r2 + k - 128);
        const float* Wk = W0 + (size_t)row * 512 + tid;
        const float wv0 = Wk[0];
        const float wv1 = Wk[512];
        const float wv2 = Wk[1024];
        const float wv3 = Wk[1536];
#pragma unroll
        for (int nn = 0; nn < NPB; ++nn) {
            const float4 x4 = *reinterpret_cast<const float4*>(&Xs[nn * 384 + k]);
            acc[nn] = fmaf(x4.x, wv0, acc[nn]);
            acc[nn] = fmaf(x4.y, wv1, acc[nn]);
            acc[nn] = fmaf(x4.z, wv2, acc[nn]);
            acc[nn] = fmaf(x4.w, wv3, acc[nn]);
        }
    }
#pragma unroll
    for (int nn = 0; nn < NPB; ++nn) Y[(size_t)(n0 + nn) * 512 + tid] = acc[nn];
}

// ------------------------------ GATv2 pieces -------------------------------
__global__ void gat_logits_kernel(const float* __restrict__ fs, const float* __restrict__ fd,
                                  const float* __restrict__ attn, const int* __restrict__ src,
                                  const int* __restrict__ dst, float* __restrict__ logits) {
    const int wave = threadIdx.x >> 6;
    const int lane = threadIdx.x & 63;
    const int e = blockIdx.x * 4 + wave;
    if (e >= N_EDGES) return;
    const int s = src[e], d = dst[e];
    const float4 a  = *reinterpret_cast<const float4*>(&fs[s * 256 + lane * 4]);
    const float4 b  = *reinterpret_cast<const float4*>(&fd[d * 256 + lane * 4]);
    const float4 at = *reinterpret_cast<const float4*>(&attn[lane * 4]);
    float p = lrelu(a.x + b.x) * at.x;
    p = fmaf(lrelu(a.y + b.y), at.y, p);
    p = fmaf(lrelu(a.z + b.z), at.z, p);
    p = fmaf(lrelu(a.w + b.w), at.w, p);
    for (int off = 1; off < 32; off <<= 1) p += __shfl_xor(p, off);
    if ((lane & 31) == 0) logits[e * 2 + (lane >> 5)] = p;
}

__global__ void gat_agg_kernel(const float* __restrict__ fs, const float* __restrict__ logits,
                               const int* __restrict__ eidx, const int* __restrict__ row_off,
                               const int* __restrict__ src, float* __restrict__ out) {
    const int wave = threadIdx.x >> 6;
    const int lane = threadIdx.x & 63;
    const int id = blockIdx.x * 4 + wave;
    const int n = id >> 1, h = id & 1;
    const int s0 = row_off[n], s1 = row_off[n + 1];
    float m = -INFINITY;
    for (int i = s0; i < s1; ++i) m = fmaxf(m, logits[eidx[i] * 2 + h]);
    float ssum = 0.f, a0 = 0.f, a1 = 0.f;
    for (int i = s0; i < s1; ++i) {
        const int e = eidx[i];
        const float w = __expf(logits[e * 2 + h] - m);
        ssum += w;
        const float2 v = *reinterpret_cast<const float2*>(
            &fs[src[e] * 256 + h * 128 + lane * 2]);
        a0 = fmaf(w, v.x, a0);
        a1 = fmaf(w, v.y, a1);
    }
    const float inv = (s1 > s0) ? 1.f / ssum : 0.f;
    out[n * 256 + h * 128 + lane * 2]     = fmaxf(a0 * inv, 0.f);
    out[n * 256 + h * 128 + lane * 2 + 1] = fmaxf(a1 * inv, 0.f);
}

// --------------------- W1 prepack into MFMA B-fragments --------------------
// Wp[s(32 k-steps)][jt(8 j-tiles)][lane(64)][8 fp16], hi and lo buffers.
// B-frag (32x32x16): lane l holds B[k = s*16 + (l>>5)*8 + i][n = jt*32 + (l&31)].
__global__ void prepack_w1_kernel(const float* __restrict__ w1,
                                  _Float16* __restrict__ WpH,
                                  _Float16* __restrict__ WpL) {
    const int idx = blockIdx.x * 256 + threadIdx.x;     // 16384 total
    const int l   = idx & 63;
    const int jt  = (idx >> 6) & 7;
    const int s   = idx >> 9;
    const int j   = jt * 32 + (l & 31);
    const int kb  = s * 16 + (l >> 5) * 8;
    half8 vh, vl;
#pragma unroll
    for (int i = 0; i < 8; ++i) {
        const float w = w1[(size_t)(kb + i) * 256 + j];
        const _Float16 h = (_Float16)w;
        vh[i] = h;
        vl[i] = (_Float16)(w - (float)h);
    }
    reinterpret_cast<half8*>(WpH)[idx] = vh;
    reinterpret_cast<half8*>(WpL)[idx] = vl;
}

// ------------------------------ fused EdgeMLP ------------------------------
// Block = 64 edges, 4 waves: (e-group, j-group) in 2x2. Each wave: 32e x 128j.
// x = relu(S[src]+D[dst]) split to fp16 hi/lo entirely in registers (lane
// (m=l&31, h=l>>5) owns exactly its A-fragment k-octet). Layer-1 via
// 3x v_mfma_f32_32x32x16_f16 per tile; layer-2 folded into register epilogue.
__global__ __launch_bounds__(256, 4) void edge_mlp3_kernel(
    const float* __restrict__ S, const float* __restrict__ Dn,
    const int* __restrict__ src, const int* __restrict__ dst,
    const _Float16* __restrict__ WpH, const _Float16* __restrict__ WpL,
    const float* __restrict__ b1, const float* __restrict__ w2,
    const float* __restrict__ b2, float* __restrict__ out) {
    __shared__ float q[2][64];
    const int tid = threadIdx.x;
    const int wv  = tid >> 6;
    const int l   = tid & 63;
    const int eg  = wv & 1, jg = wv >> 1;
    const int m   = l & 31;                 // A row (edge) / B-C col (j)
    const int h   = l >> 5;                 // k-octet selector
    const int e0  = blockIdx.x * 64;
    const int e   = e0 + eg * 32 + m;
    const float* __restrict__ Srow = S  + (size_t)src[e] * 512;
    const float* __restrict__ Drow = Dn + (size_t)dst[e] * 512;
    const half8* __restrict__ BH = reinterpret_cast<const half8*>(WpH);
    const half8* __restrict__ BL = reinterpret_cast<const half8*>(WpL);

    f32x16 acc[4];
#pragma unroll
    for (int jt = 0; jt < 4; ++jt) {
        const float bv = b1[jg * 128 + jt * 32 + m];
#pragma unroll
        for (int r = 0; r < 16; ++r) acc[jt][r] = bv;
    }

    // prefetch s=0
    float4 sa = *reinterpret_cast<const float4*>(Srow + h * 8);
    float4 sb = *reinterpret_cast<const float4*>(Srow + h * 8 + 4);
    float4 da = *reinterpret_cast<const float4*>(Drow + h * 8);
    float4 db = *reinterpret_cast<const float4*>(Drow + h * 8 + 4);

    for (int s = 0; s < 32; ++s) {
        float xs[8] = {sa.x + da.x, sa.y + da.y, sa.z + da.z, sa.w + da.w,
                       sb.x + db.x, sb.y + db.y, sb.z + db.z, sb.w + db.w};
        if (s < 31) {                       // prefetch next k16-step
            const int ko = (s + 1) * 16 + h * 8;
            sa = *reinterpret_cast<const float4*>(Srow + ko);
            sb = *reinterpret_cast<const float4*>(Srow + ko + 4);
            da = *reinterpret_cast<const float4*>(Drow + ko);
            db = *reinterpret_cast<const float4*>(Drow + ko + 4);
        }
        half8 ah, al;
#pragma unroll
        for (int i = 0; i < 8; ++i) {
            const float xv = fmaxf(xs[i], 0.f);
            const _Float16 hi = (_Float16)xv;
            ah[i] = hi;
            al[i] = (_Float16)(xv - (float)hi);
        }
#pragma unroll
        for (int jt = 0; jt < 4; ++jt) {
            const int fi = (s * 8 + jg * 4 + jt) * 64 + l;
            const half8 bh = BH[fi];
            const half8 bl = BL[fi];
            acc[jt] = __builtin_amdgcn_mfma_f32_32x32x16_f16(ah, bh, acc[jt], 0, 0, 0);
            acc[jt] = __builtin_amdgcn_mfma_f32_32x32x16_f16(al, bh, acc[jt], 0, 0, 0);
            acc[jt] = __builtin_amdgcn_mfma_f32_32x32x16_f16(ah, bl, acc[jt], 0, 0, 0);
        }
    }

    // ---- layer 2 folded: part[r] = sum_j relu(y1)*w2[j] over this wave's j ----
    float part[16];
#pragma unroll
    for (int r = 0; r < 16; ++r) part[r] = 0.f;
#pragma unroll
    for (int jt = 0; jt < 4; ++jt) {
        const float w2v = w2[jg * 128 + jt * 32 + m];
#pragma unroll
        for (int r = 0; r < 16; ++r)
            part[r] = fmaf(fmaxf(acc[jt][r], 0.f), w2v, part[r]);
    }
#pragma unroll
    for (int off = 1; off < 32; off <<= 1)
#pragma unroll
        for (int r = 0; r < 16; ++r) part[r] += __shfl_xor(part[r], off);
    if (m == 0) {
#pragma unroll
        for (int r = 0; r < 16; ++r) {
            const int row = (r & 3) + 8 * (r >> 2) + 4 * h;   // C/D row mapping
            q[jg][eg * 32 + row] = part[r];
        }
    }
    __syncthreads();
    if (tid < 64) out[e0 + tid] = q[0][tid] + q[1][tid] + b2[0];
}

// ------------------------------ launch ------------------------------------
extern "C" void kernel_launch(void* const* d_in, const int* in_sizes, int n_in,
                              void* d_out, int out_size, void* d_ws, size_t ws_size,
                              hipStream_t stream) {
    (void)in_sizes; (void)n_in; (void)out_size; (void)ws_size;
    const float* x    = (const float*)d_in[0];
    const int*   src  = (const int*)d_in[1];
    const int*   dst  = (const int*)d_in[2];
    const float* nw0  = (const float*)d_in[3];
    const float* nb0  = (const float*)d_in[4];
    const float* nw1  = (const float*)d_in[5];
    const float* nb1  = (const float*)d_in[6];
    const float* g1ws = (const float*)d_in[7];
    const float* g1bs = (const float*)d_in[8];
    const float* g1wd = (const float*)d_in[9];
    const float* g1bd = (const float*)d_in[10];
    const float* g1a  = (const float*)d_in[11];
    const float* g2ws = (const float*)d_in[12];
    const float* g2bs = (const float*)d_in[13];
    const float* g2wd = (const float*)d_in[14];
    const float* g2bd = (const float*)d_in[15];
    const float* g2a  = (const float*)d_in[16];
    const float* ew0  = (const float*)d_in[17];
    const float* eb0  = (const float*)d_in[18];
    const float* ew1  = (const float*)d_in[19];
    const float* eb1  = (const float*)d_in[20];
    const float* ew2  = (const float*)d_in[21];
    const float* eb2  = (const float*)d_in[22];
    float* out = (float*)d_out;

    float* wsF = (float*)d_ws;
    float* h1  = wsF;                       // 20000*128
    float* g2o = wsF + 2560000;             // 20000*256
    float* fsb = wsF + 7680000;             // 20000*256
    float* fdb = wsF + 12800000;            // 20000*256
    float* g1o = wsF + 17920000;            // 20000*256
    float* lg  = wsF + 23040000;            // 320000*2
    float* Sb  = wsF + 7680000;             // 20000*512 overlays fsb+fdb (dead)
    float* Db  = wsF + 17920000;            // 20000*512 overlays g1o+lg (dead)
    int* wsI     = (int*)(wsF + 28160000);
    int* row_off = wsI;                     // 20001 (padded to 20016)
    int* cursor  = wsI + 20016;             // 20000
    int* eidx    = wsI + 40016;             // 320000 (dead after gat_agg L2)
    int* bsum    = wsI + 360016;            // 256
    // W1 fragment buffers overlay eidx (dead by prepack time): 2 x 64 Ki halves
    _Float16* WpH = (_Float16*)(wsI + 40016);
    _Float16* WpL = (_Float16*)(wsI + 40016 + 65536);

    // ---- CSR build (edges grouped by dst) ----
    hipMemsetAsync(cursor, 0, N_NODES * sizeof(int), stream);
    hist_kernel<<<1250, 256, 0, stream>>>(dst, cursor);
    scan1_kernel<<<NBLK, 256, 0, stream>>>(cursor, row_off, bsum);
    scan2_kernel<<<1, 128, 0, stream>>>(bsum);
    scan3_kernel<<<NBLK, 256, 0, stream>>>(row_off, bsum, cursor);
    scatter_kernel<<<1250, 256, 0, stream>>>(dst, cursor, eidx);

    // ---- NodeMLP ----
    linear_kernel<64, 128, 8, true><<<2500, 128, 0, stream>>>(x, nw0, nb0, fsb, N_NODES);
    linear_kernel<128, 128, 8, true><<<2500, 128, 0, stream>>>(fsb, nw1, nb1, h1, N_NODES);

    // ---- GATv2 layer 1 ----
    linear_kernel<64, 256, 8, false><<<2500, 256, 0, stream>>>(x, g1ws, g1bs, fsb, N_NODES);
    linear_kernel<64, 256, 8, false><<<2500, 256, 0, stream>>>(x, g1wd, g1bd, fdb, N_NODES);
    gat_logits_kernel<<<N_EDGES / 4, 256, 0, stream>>>(fsb, fdb, g1a, src, dst, lg);
    gat_agg_kernel<<<N_NODES * 2 / 4, 256, 0, stream>>>(fsb, lg, eidx, row_off, src, g1o);

    // ---- GATv2 layer 2 ----
    linear_kernel<256, 256, 8, false><<<2500, 256, 0, stream>>>(g1o, g2ws, g2bs, fsb, N_NODES);
    linear_kernel<256, 256, 8, false><<<2500, 256, 0, stream>>>(g1o, g2wd, g2bd, fdb, N_NODES);
    gat_logits_kernel<<<N_EDGES / 4, 256, 0, stream>>>(fsb, fdb, g2a, src, dst, lg);
    gat_agg_kernel<<<N_NODES * 2 / 4, 256, 0, stream>>>(fsb, lg, eidx, row_off, src, g2o);
    // eidx/row_off/cursor dead from here.

    // ---- W1 prepack (overlays eidx) ----
    prepack_w1_kernel<<<64, 256, 0, stream>>>(ew1, WpH, WpL);

    // ---- S/D precompute (EdgeMLP layer-0 decomposition) ----
    linear_sd_kernel<false><<<1250, 512, 0, stream>>>(h1, g2o, ew0, 0, 256, nullptr, Sb);
    linear_sd_kernel<true><<<1250, 512, 0, stream>>>(h1, g2o, ew0, 128, 512, eb0, Db);

    // ---- fused EdgeMLP: relu(S[src]+D[dst]) -> MFMA 512x256 -> relu -> 256x1 ----
    edge_mlp3_kernel<<<N_EDGES / 64, 256, 0, stream>>>(Sb, Db, src, dst, WpH, WpL,
                                                       eb1, ew2, eb2, out);
}

// Round 4
// 1067.027 us; speedup vs baseline: 5.7669x; 1.4254x over previous
//
#include <hip/hip_runtime.h>
#include <hip/hip_bf16.h>

// ---------------------------------------------------------------------------
// EdgePredModel: NodeMLP + 2x GATv2 + EdgeMLP.
// R4: fused flash-style GAT (one wave/node, online softmax, CSR order);
//     edge MLP processes edges dst-sorted for D-row L1 reuse.
// ---------------------------------------------------------------------------
constexpr int N_NODES = 20000;
constexpr int N_EDGES = 320000;
constexpr int NBLK    = (N_NODES + 255) / 256;   // 79 (scan blocks)

typedef _Float16 half8 __attribute__((ext_vector_type(8)));
typedef float    f32x16 __attribute__((ext_vector_type(16)));

__device__ __forceinline__ float lrelu(float x) { return x > 0.f ? x : 0.2f * x; }

// ------------------------------ CSR build ---------------------------------
__global__ void hist_kernel(const int* __restrict__ dst, int* __restrict__ counts) {
    int e = blockIdx.x * 256 + threadIdx.x;
    if (e < N_EDGES) atomicAdd(&counts[dst[e]], 1);
}

__global__ void scan1_kernel(const int* __restrict__ counts, int* __restrict__ partial,
                             int* __restrict__ bsum) {
    __shared__ int s[256];
    int i = blockIdx.x * 256 + threadIdx.x;
    int v = (i < N_NODES) ? counts[i] : 0;
    s[threadIdx.x] = v;
    __syncthreads();
    for (int off = 1; off < 256; off <<= 1) {
        int t = (threadIdx.x >= off) ? s[threadIdx.x - off] : 0;
        __syncthreads();
        s[threadIdx.x] += t;
        __syncthreads();
    }
    if (i < N_NODES) partial[i] = s[threadIdx.x] - v;     // exclusive within block
    if (threadIdx.x == 255) bsum[blockIdx.x] = s[255];    // block total
}

__global__ void scan2_kernel(int* __restrict__ bsum) {
    __shared__ int s[128];
    int b = threadIdx.x;
    int v = (b < NBLK) ? bsum[b] : 0;
    s[b] = v;
    __syncthreads();
    for (int off = 1; off < 128; off <<= 1) {
        int t = (b >= off) ? s[b - off] : 0;
        __syncthreads();
        s[b] += t;
        __syncthreads();
    }
    if (b < NBLK) bsum[128 + b] = s[b] - v;               // exclusive block offsets
}

__global__ void scan3_kernel(int* __restrict__ row_off, const int* __restrict__ bsum,
                             int* __restrict__ cursor) {
    int i = blockIdx.x * 256 + threadIdx.x;
    if (i < N_NODES) {
        int v = row_off[i] + bsum[128 + blockIdx.x];
        row_off[i] = v;
        cursor[i]  = v;
    }
    if (i == 0) row_off[N_NODES] = N_EDGES;
}

// also emits srcs[p] = src[e] so consumers skip one indirection hop
__global__ void scatter_kernel(const int* __restrict__ src, const int* __restrict__ dst,
                               int* __restrict__ cursor, int* __restrict__ eidx,
                               int* __restrict__ srcs) {
    int e = blockIdx.x * 256 + threadIdx.x;
    if (e < N_EDGES) {
        int p = atomicAdd(&cursor[dst[e]], 1);
        eidx[p] = e;
        srcs[p] = src[e];
    }
}

// ------------------------------ dense linear -------------------------------
template <int K, int M, int NPB, bool RELU>
__global__ void linear_kernel(const float* __restrict__ X, const float* __restrict__ W,
                              const float* __restrict__ bias, float* __restrict__ Y,
                              int N) {
    __shared__ float Xs[NPB * K];
    const int tid = threadIdx.x;
    const int n0  = blockIdx.x * NPB;
    for (int idx = tid; idx < NPB * K; idx += M)
        Xs[idx] = X[n0 * K + idx];
    __syncthreads();
    float acc[NPB];
    const float bj = bias[tid];
#pragma unroll
    for (int nn = 0; nn < NPB; ++nn) acc[nn] = bj;
    for (int k = 0; k < K; k += 4) {
        float wv0 = W[(k + 0) * M + tid];
        float wv1 = W[(k + 1) * M + tid];
        float wv2 = W[(k + 2) * M + tid];
        float wv3 = W[(k + 3) * M + tid];
#pragma unroll
        for (int nn = 0; nn < NPB; ++nn) {
            const float4 x4 = *reinterpret_cast<const float4*>(&Xs[nn * K + k]);
            acc[nn] = fmaf(x4.x, wv0, acc[nn]);
            acc[nn] = fmaf(x4.y, wv1, acc[nn]);
            acc[nn] = fmaf(x4.z, wv2, acc[nn]);
            acc[nn] = fmaf(x4.w, wv3, acc[nn]);
        }
    }
#pragma unroll
    for (int nn = 0; nn < NPB; ++nn) {
        float v = acc[nn];
        if (RELU) v = fmaxf(v, 0.f);
        Y[(n0 + nn) * M + tid] = v;
    }
}

// -------------------- S/D precompute for EdgeMLP layer-0 -------------------
template <bool HASB>
__global__ void linear_sd_kernel(const float* __restrict__ X1,  // (N,128)
                                 const float* __restrict__ X2,  // (N,256)
                                 const float* __restrict__ W0,  // (768,512)
                                 int r1, int r2,
                                 const float* __restrict__ bias,
                                 float* __restrict__ Y) {       // (N,512)
    constexpr int NPB = 16;
    __shared__ float Xs[NPB * 384];
    const int tid = threadIdx.x;
    const int n0  = blockIdx.x * NPB;
    for (int idx = tid; idx < NPB * 384; idx += 512) {
        const int nn = idx / 384, k = idx - nn * 384;
        Xs[idx] = (k < 128) ? X1[(n0 + nn) * 128 + k]
                            : X2[(n0 + nn) * 256 + (k - 128)];
    }
    __syncthreads();
    float acc[NPB];
    const float bj = HASB ? bias[tid] : 0.f;
#pragma unroll
    for (int nn = 0; nn < NPB; ++nn) acc[nn] = bj;
    for (int k = 0; k < 384; k += 4) {
        const int row = (k < 128) ? (r1 + k) : (r2 + k - 128);
        const float* Wk = W0 + (size_t)row * 512 + tid;
        const float wv0 = Wk[0];
        const float wv1 = Wk[512];
        const float wv2 = Wk[1024];
        const float wv3 = Wk[1536];
#pragma unroll
        for (int nn = 0; nn < NPB; ++nn) {
            const float4 x4 = *reinterpret_cast<const float4*>(&Xs[nn * 384 + k]);
            acc[nn] = fmaf(x4.x, wv0, acc[nn]);
            acc[nn] = fmaf(x4.y, wv1, acc[nn]);
            acc[nn] = fmaf(x4.z, wv2, acc[nn]);
            acc[nn] = fmaf(x4.w, wv3, acc[nn]);
        }
    }
#pragma unroll
    for (int nn = 0; nn < NPB; ++nn) Y[(size_t)(n0 + nn) * 512 + tid] = acc[nn];
}

// --------------------------- fused GATv2 layer -----------------------------
// One wave per node, both heads: lanes 0..31 = head 0 (4 dims/lane),
// lanes 32..63 = head 1. fd row + attn loaded once; per in-edge a single
// float4 fs[src] load feeds logit AND aggregation (online softmax).
__global__ void gat_fused_kernel(const float* __restrict__ fs, const float* __restrict__ fd,
                                 const float* __restrict__ attn,
                                 const int* __restrict__ row_off,
                                 const int* __restrict__ srcs,
                                 float* __restrict__ outp) {
    const int wv = threadIdx.x >> 6, l = threadIdx.x & 63;
    const int n = blockIdx.x * 4 + wv;
    if (n >= N_NODES) return;
    const int base = (l >> 5) * 128 + (l & 31) * 4;    // h*128 + d
    const float4 fdv = *reinterpret_cast<const float4*>(&fd[n * 256 + base]);
    const float4 av  = *reinterpret_cast<const float4*>(&attn[base]);
    const int s0 = row_off[n], s1 = row_off[n + 1];

    float m = -INFINITY, lsum = 0.f;
    float4 acc = {0.f, 0.f, 0.f, 0.f};
    float4 v;
    if (s0 < s1)
        v = *reinterpret_cast<const float4*>(&fs[(size_t)srcs[s0] * 256 + base]);
    for (int i = s0; i < s1; ++i) {
        const float4 vc = v;
        if (i + 1 < s1)                                  // depth-1 pipeline
            v = *reinterpret_cast<const float4*>(&fs[(size_t)srcs[i + 1] * 256 + base]);
        float p = lrelu(vc.x + fdv.x) * av.x;
        p = fmaf(lrelu(vc.y + fdv.y), av.y, p);
        p = fmaf(lrelu(vc.z + fdv.z), av.z, p);
        p = fmaf(lrelu(vc.w + fdv.w), av.w, p);
#pragma unroll
        for (int off = 1; off < 32; off <<= 1) p += __shfl_xor(p, off);
        const float mn = fmaxf(m, p);
        const float alpha = __expf(m - mn);              // first iter: exp(-inf)=0
        const float w = __expf(p - mn);
        lsum = fmaf(lsum, alpha, w);
        acc.x = fmaf(acc.x, alpha, w * vc.x);
        acc.y = fmaf(acc.y, alpha, w * vc.y);
        acc.z = fmaf(acc.z, alpha, w * vc.z);
        acc.w = fmaf(acc.w, alpha, w * vc.w);
        m = mn;
    }
    const float inv = (s1 > s0) ? 1.f / lsum : 0.f;
    float4 o;
    o.x = fmaxf(acc.x * inv, 0.f);
    o.y = fmaxf(acc.y * inv, 0.f);
    o.z = fmaxf(acc.z * inv, 0.f);
    o.w = fmaxf(acc.w * inv, 0.f);
    *reinterpret_cast<float4*>(&outp[n * 256 + base]) = o;
}

// --------------------- W1 prepack into MFMA B-fragments --------------------
__global__ void prepack_w1_kernel(const float* __restrict__ w1,
                                  _Float16* __restrict__ WpH,
                                  _Float16* __restrict__ WpL) {
    const int idx = blockIdx.x * 256 + threadIdx.x;     // 16384 total
    const int l   = idx & 63;
    const int jt  = (idx >> 6) & 7;
    const int s   = idx >> 9;
    const int j   = jt * 32 + (l & 31);
    const int kb  = s * 16 + (l >> 5) * 8;
    half8 vh, vl;
#pragma unroll
    for (int i = 0; i < 8; ++i) {
        const float w = w1[(size_t)(kb + i) * 256 + j];
        const _Float16 h = (_Float16)w;
        vh[i] = h;
        vl[i] = (_Float16)(w - (float)h);
    }
    reinterpret_cast<half8*>(WpH)[idx] = vh;
    reinterpret_cast<half8*>(WpL)[idx] = vl;
}

// ------------------------------ fused EdgeMLP ------------------------------
// Processes edges in dst-sorted (CSR) order: slot -> (srcs[slot], dst[eidx[slot]]),
// so consecutive lanes share D rows (L1 broadcast hits). Split-fp16 MFMA layer-1,
// layer-2 folded into register epilogue; out written scattered via eidx.
__global__ __launch_bounds__(256, 4) void edge_mlp3_kernel(
    const float* __restrict__ S, const float* __restrict__ Dn,
    const int* __restrict__ srcs, const int* __restrict__ eidx,
    const int* __restrict__ dstf,
    const _Float16* __restrict__ WpH, const _Float16* __restrict__ WpL,
    const float* __restrict__ b1, const float* __restrict__ w2,
    const float* __restrict__ b2, float* __restrict__ out) {
    __shared__ float q[2][64];
    const int tid = threadIdx.x;
    const int wv  = tid >> 6;
    const int l   = tid & 63;
    const int eg  = wv & 1, jg = wv >> 1;
    const int m   = l & 31;                 // A row (edge) / B-C col (j)
    const int h   = l >> 5;                 // k-octet selector
    const int e0  = blockIdx.x * 64;
    const int slot = e0 + eg * 32 + m;
    const float* __restrict__ Srow = S  + (size_t)srcs[slot] * 512;
    const float* __restrict__ Drow = Dn + (size_t)dstf[eidx[slot]] * 512;
    const half8* __restrict__ BH = reinterpret_cast<const half8*>(WpH);
    const half8* __restrict__ BL = reinterpret_cast<const half8*>(WpL);

    f32x16 acc[4];
#pragma unroll
    for (int jt = 0; jt < 4; ++jt) {
        const float bv = b1[jg * 128 + jt * 32 + m];
#pragma unroll
        for (int r = 0; r < 16; ++r) acc[jt][r] = bv;
    }

    // prefetch s=0
    float4 sa = *reinterpret_cast<const float4*>(Srow + h * 8);
    float4 sb = *reinterpret_cast<const float4*>(Srow + h * 8 + 4);
    float4 da = *reinterpret_cast<const float4*>(Drow + h * 8);
    float4 db = *reinterpret_cast<const float4*>(Drow + h * 8 + 4);

    for (int s = 0; s < 32; ++s) {
        float xs[8] = {sa.x + da.x, sa.y + da.y, sa.z + da.z, sa.w + da.w,
                       sb.x + db.x, sb.y + db.y, sb.z + db.z, sb.w + db.w};
        if (s < 31) {                       // prefetch next k16-step
            const int ko = (s + 1) * 16 + h * 8;
            sa = *reinterpret_cast<const float4*>(Srow + ko);
            sb = *reinterpret_cast<const float4*>(Srow + ko + 4);
            da = *reinterpret_cast<const float4*>(Drow + ko);
            db = *reinterpret_cast<const float4*>(Drow + ko + 4);
        }
        half8 ah, al;
#pragma unroll
        for (int i = 0; i < 8; ++i) {
            const float xv = fmaxf(xs[i], 0.f);
            const _Float16 hi = (_Float16)xv;
            ah[i] = hi;
            al[i] = (_Float16)(xv - (float)hi);
        }
#pragma unroll
        for (int jt = 0; jt < 4; ++jt) {
            const int fi = (s * 8 + jg * 4 + jt) * 64 + l;
            const half8 bh = BH[fi];
            const half8 bl = BL[fi];
            acc[jt] = __builtin_amdgcn_mfma_f32_32x32x16_f16(ah, bh, acc[jt], 0, 0, 0);
            acc[jt] = __builtin_amdgcn_mfma_f32_32x32x16_f16(al, bh, acc[jt], 0, 0, 0);
            acc[jt] = __builtin_amdgcn_mfma_f32_32x32x16_f16(ah, bl, acc[jt], 0, 0, 0);
        }
    }

    // ---- layer 2 folded: part[r] = sum_j relu(y1)*w2[j] over this wave's j ----
    float part[16];
#pragma unroll
    for (int r = 0; r < 16; ++r) part[r] = 0.f;
#pragma unroll
    for (int jt = 0; jt < 4; ++jt) {
        const float w2v = w2[jg * 128 + jt * 32 + m];
#pragma unroll
        for (int r = 0; r < 16; ++r)
            part[r] = fmaf(fmaxf(acc[jt][r], 0.f), w2v, part[r]);
    }
#pragma unroll
    for (int off = 1; off < 32; off <<= 1)
#pragma unroll
        for (int r = 0; r < 16; ++r) part[r] += __shfl_xor(part[r], off);
    if (m == 0) {
#pragma unroll
        for (int r = 0; r < 16; ++r) {
            const int row = (r & 3) + 8 * (r >> 2) + 4 * h;   // C/D row mapping
            q[jg][eg * 32 + row] = part[r];
        }
    }
    __syncthreads();
    if (tid < 64) out[eidx[e0 + tid]] = q[0][tid] + q[1][tid] + b2[0];
}

// ------------------------------ launch ------------------------------------
extern "C" void kernel_launch(void* const* d_in, const int* in_sizes, int n_in,
                              void* d_out, int out_size, void* d_ws, size_t ws_size,
                              hipStream_t stream) {
    (void)in_sizes; (void)n_in; (void)out_size; (void)ws_size;
    const float* x    = (const float*)d_in[0];
    const int*   src  = (const int*)d_in[1];
    const int*   dst  = (const int*)d_in[2];
    const float* nw0  = (const float*)d_in[3];
    const float* nb0  = (const float*)d_in[4];
    const float* nw1  = (const float*)d_in[5];
    const float* nb1  = (const float*)d_in[6];
    const float* g1ws = (const float*)d_in[7];
    const float* g1bs = (const float*)d_in[8];
    const float* g1wd = (const float*)d_in[9];
    const float* g1bd = (const float*)d_in[10];
    const float* g1a  = (const float*)d_in[11];
    const float* g2ws = (const float*)d_in[12];
    const float* g2bs = (const float*)d_in[13];
    const float* g2wd = (const float*)d_in[14];
    const float* g2bd = (const float*)d_in[15];
    const float* g2a  = (const float*)d_in[16];
    const float* ew0  = (const float*)d_in[17];
    const float* eb0  = (const float*)d_in[18];
    const float* ew1  = (const float*)d_in[19];
    const float* eb1  = (const float*)d_in[20];
    const float* ew2  = (const float*)d_in[21];
    const float* eb2  = (const float*)d_in[22];
    float* out = (float*)d_out;

    float* wsF = (float*)d_ws;
    float* h1  = wsF;                       // 20000*128  (dead after linear_sd)
    float* g2o = wsF + 2560000;             // 20000*256
    float* fsb = wsF + 7680000;             // 20000*256
    float* fdb = wsF + 12800000;            // 20000*256
    float* g1o = wsF + 17920000;            // 20000*256
    float* Sb  = wsF + 7680000;             // 20000*512 overlays fsb+fdb (dead)
    float* Db  = wsF + 17920000;            // 20000*512 overlays g1o (dead)
    int* wsI     = (int*)(wsF + 28160000);
    int* row_off = wsI;                     // [0, 20016)
    int* cursor  = wsI + 20016;             // [20016, 40032)
    int* eidx    = wsI + 40032;             // [40032, 360032)
    int* srcs    = wsI + 360032;            // [360032, 680032)
    int* bsum    = wsI + 680032;            // [680032, 680288)
    // W1 fragment buffers overlay h1 (dead after linear_sd): 2 x 256 KiB
    _Float16* WpH = (_Float16*)h1;
    _Float16* WpL = (_Float16*)h1 + 131072;

    // ---- CSR build (edges grouped by dst) ----
    hipMemsetAsync(cursor, 0, N_NODES * sizeof(int), stream);
    hist_kernel<<<1250, 256, 0, stream>>>(dst, cursor);
    scan1_kernel<<<NBLK, 256, 0, stream>>>(cursor, row_off, bsum);
    scan2_kernel<<<1, 128, 0, stream>>>(bsum);
    scan3_kernel<<<NBLK, 256, 0, stream>>>(row_off, bsum, cursor);
    scatter_kernel<<<1250, 256, 0, stream>>>(src, dst, cursor, eidx, srcs);

    // ---- NodeMLP ----
    linear_kernel<64, 128, 8, true><<<2500, 128, 0, stream>>>(x, nw0, nb0, fsb, N_NODES);
    linear_kernel<128, 128, 8, true><<<2500, 128, 0, stream>>>(fsb, nw1, nb1, h1, N_NODES);

    // ---- GATv2 layer 1 (fc + fused attention/aggregate) ----
    linear_kernel<64, 256, 8, false><<<2500, 256, 0, stream>>>(x, g1ws, g1bs, fsb, N_NODES);
    linear_kernel<64, 256, 8, false><<<2500, 256, 0, stream>>>(x, g1wd, g1bd, fdb, N_NODES);
    gat_fused_kernel<<<5000, 256, 0, stream>>>(fsb, fdb, g1a, row_off, srcs, g1o);

    // ---- GATv2 layer 2 ----
    linear_kernel<256, 256, 8, false><<<2500, 256, 0, stream>>>(g1o, g2ws, g2bs, fsb, N_NODES);
    linear_kernel<256, 256, 8, false><<<2500, 256, 0, stream>>>(g1o, g2wd, g2bd, fdb, N_NODES);
    gat_fused_kernel<<<5000, 256, 0, stream>>>(fsb, fdb, g2a, row_off, srcs, g2o);

    // ---- S/D precompute (EdgeMLP layer-0 decomposition) ----
    linear_sd_kernel<false><<<1250, 512, 0, stream>>>(h1, g2o, ew0, 0, 256, nullptr, Sb);
    linear_sd_kernel<true><<<1250, 512, 0, stream>>>(h1, g2o, ew0, 128, 512, eb0, Db);

    // ---- W1 prepack (overlays h1, dead now) ----
    prepack_w1_kernel<<<64, 256, 0, stream>>>(ew1, WpH, WpL);

    // ---- fused EdgeMLP: relu(S[src]+D[dst]) -> MFMA 512x256 -> relu -> 256x1 ----
    edge_mlp3_kernel<<<N_EDGES / 64, 256, 0, stream>>>(Sb, Db, srcs, eidx, dst,
                                                       WpH, WpL, eb1, ew2, eb2, out);
}

// Round 5
// 827.003 us; speedup vs baseline: 7.4407x; 1.2902x over previous
//
#include <hip/hip_runtime.h>
#include <hip/hip_bf16.h>

// ---------------------------------------------------------------------------
// EdgePredModel: NodeMLP + 2x GATv2 + EdgeMLP.
// R5: ALL node-side GEMMs converted to split-fp16 MFMA (3-product fp32
//     emulation, 32x32x16_f16) via one templated kernel; W prepacked to
//     B-fragments. gat_fused gets depth-2 prefetch. Edge kernel unchanged.
// ---------------------------------------------------------------------------
constexpr int N_NODES = 20000;
constexpr int N_EDGES = 320000;
constexpr int NBLK    = (N_NODES + 255) / 256;   // 79 (scan blocks)

typedef _Float16 half8 __attribute__((ext_vector_type(8)));
typedef float    f32x16 __attribute__((ext_vector_type(16)));

__device__ __forceinline__ float lrelu(float x) { return x > 0.f ? x : 0.2f * x; }

// ------------------------------ CSR build ---------------------------------
__global__ void hist_kernel(const int* __restrict__ dst, int* __restrict__ counts) {
    int e = blockIdx.x * 256 + threadIdx.x;
    if (e < N_EDGES) atomicAdd(&counts[dst[e]], 1);
}

__global__ void scan1_kernel(const int* __restrict__ counts, int* __restrict__ partial,
                             int* __restrict__ bsum) {
    __shared__ int s[256];
    int i = blockIdx.x * 256 + threadIdx.x;
    int v = (i < N_NODES) ? counts[i] : 0;
    s[threadIdx.x] = v;
    __syncthreads();
    for (int off = 1; off < 256; off <<= 1) {
        int t = (threadIdx.x >= off) ? s[threadIdx.x - off] : 0;
        __syncthreads();
        s[threadIdx.x] += t;
        __syncthreads();
    }
    if (i < N_NODES) partial[i] = s[threadIdx.x] - v;     // exclusive within block
    if (threadIdx.x == 255) bsum[blockIdx.x] = s[255];    // block total
}

__global__ void scan2_kernel(int* __restrict__ bsum) {
    __shared__ int s[128];
    int b = threadIdx.x;
    int v = (b < NBLK) ? bsum[b] : 0;
    s[b] = v;
    __syncthreads();
    for (int off = 1; off < 128; off <<= 1) {
        int t = (b >= off) ? s[b - off] : 0;
        __syncthreads();
        s[b] += t;
        __syncthreads();
    }
    if (b < NBLK) bsum[128 + b] = s[b] - v;               // exclusive block offsets
}

__global__ void scan3_kernel(int* __restrict__ row_off, const int* __restrict__ bsum,
                             int* __restrict__ cursor) {
    int i = blockIdx.x * 256 + threadIdx.x;
    if (i < N_NODES) {
        int v = row_off[i] + bsum[128 + blockIdx.x];
        row_off[i] = v;
        cursor[i]  = v;
    }
    if (i == 0) row_off[N_NODES] = N_EDGES;
}

__global__ void scatter_kernel(const int* __restrict__ src, const int* __restrict__ dst,
                               int* __restrict__ cursor, int* __restrict__ eidx,
                               int* __restrict__ srcs) {
    int e = blockIdx.x * 256 + threadIdx.x;
    if (e < N_EDGES) {
        int p = atomicAdd(&cursor[dst[e]], 1);
        eidx[p] = e;
        srcs[p] = src[e];
    }
}

// --------------------- generic W prepack into B-fragments ------------------
// Packs W' (K,M) where W'row(k) = W[k<k1 ? r1+k : r2+(k-k1)] into hi/lo fp16
// B-frags for 32x32x16_f16: frag fi=(s*(M/32)+t)*64+l, lane l holds
// B[k=s*16+(l>>5)*8+i][j=t*32+(l&31)], i=0..7.
template <int K, int M>
__global__ void prepack_kernel(const float* __restrict__ W, int r1, int k1, int r2,
                               _Float16* __restrict__ WpH, _Float16* __restrict__ WpL) {
    const int idx = blockIdx.x * 256 + threadIdx.x;
    if (idx >= (K / 16) * (M / 32) * 64) return;
    const int l  = idx & 63;
    const int t  = (idx >> 6) % (M / 32);
    const int s  = (idx >> 6) / (M / 32);
    const int j  = t * 32 + (l & 31);
    const int kb = s * 16 + (l >> 5) * 8;
    half8 vh, vl;
#pragma unroll
    for (int i = 0; i < 8; ++i) {
        const int k    = kb + i;
        const int rrow = (k < k1) ? (r1 + k) : (r2 + (k - k1));
        const float w  = W[(size_t)rrow * M + j];
        const _Float16 h = (_Float16)w;
        vh[i] = h;
        vl[i] = (_Float16)(w - (float)h);
    }
    reinterpret_cast<half8*>(WpH)[idx] = vh;
    reinterpret_cast<half8*>(WpL)[idx] = vl;
}

// ----------------------- split-fp16 MFMA node linear -----------------------
// Y(N,M) = act(X@W + b), X = [X1(:, :K1) | X2(:, K1:K)] row-major.
// Block: 64 rows, 4 waves in 2x2 (row-group, col-group); wave = 32r x M/2 c.
// A built in registers (lane m=l&31 -> row, h=l>>5 -> k-octet), split hi/lo;
// 3 MFMA per tile (ah*bh + al*bh + ah*bl ~ fp32 accuracy).
template <int K, int M, int K1, int LD1, int LD2, bool HASB, bool RELU, int MINW>
__global__ __launch_bounds__(256, MINW) void mfma_linear_kernel(
    const float* __restrict__ X1, const float* __restrict__ X2,
    const _Float16* __restrict__ BHp, const _Float16* __restrict__ BLp,
    const float* __restrict__ bias, float* __restrict__ Y, int N) {
    constexpr int TJ = M / 64;              // col tiles per wave
    const int tid = threadIdx.x;
    const int wv  = tid >> 6, l = tid & 63;
    const int rg  = wv & 1, cg = wv >> 1;
    const int m   = l & 31, h = l >> 5;
    const int row = blockIdx.x * 64 + rg * 32 + m;
    const int ar  = (row < N) ? row : (N - 1);
    const float* __restrict__ xr1 = X1 + (size_t)ar * LD1;
    const float* __restrict__ xr2 = X2 + (size_t)ar * LD2;
    const half8* __restrict__ BH = reinterpret_cast<const half8*>(BHp);
    const half8* __restrict__ BL = reinterpret_cast<const half8*>(BLp);

    f32x16 acc[TJ];
#pragma unroll
    for (int jt = 0; jt < TJ; ++jt) {
        const float bv = HASB ? bias[cg * (M / 2) + jt * 32 + m] : 0.f;
#pragma unroll
        for (int r = 0; r < 16; ++r) acc[jt][r] = bv;
    }

    // prefetch k-octet for s=0
    const int kf = h * 8;
    const float* pf = (kf < K1) ? (xr1 + kf) : (xr2 + (kf - K1));
    float4 xa = *reinterpret_cast<const float4*>(pf);
    float4 xb = *reinterpret_cast<const float4*>(pf + 4);

    for (int s = 0; s < K / 16; ++s) {
        const float xs[8] = {xa.x, xa.y, xa.z, xa.w, xb.x, xb.y, xb.z, xb.w};
        if (s + 1 < K / 16) {
            const int kn = (s + 1) * 16 + h * 8;
            const float* pn = (kn < K1) ? (xr1 + kn) : (xr2 + (kn - K1));
            xa = *reinterpret_cast<const float4*>(pn);
            xb = *reinterpret_cast<const float4*>(pn + 4);
        }
        half8 ah, al;
#pragma unroll
        for (int i = 0; i < 8; ++i) {
            const _Float16 hi = (_Float16)xs[i];
            ah[i] = hi;
            al[i] = (_Float16)(xs[i] - (float)hi);
        }
#pragma unroll
        for (int jt = 0; jt < TJ; ++jt) {
            const int fi = (s * (M / 32) + cg * TJ + jt) * 64 + l;
            const half8 bh = BH[fi];
            const half8 bl = BL[fi];
            acc[jt] = __builtin_amdgcn_mfma_f32_32x32x16_f16(ah, bh, acc[jt], 0, 0, 0);
            acc[jt] = __builtin_amdgcn_mfma_f32_32x32x16_f16(al, bh, acc[jt], 0, 0, 0);
            acc[jt] = __builtin_amdgcn_mfma_f32_32x32x16_f16(ah, bl, acc[jt], 0, 0, 0);
        }
    }

    // store: C[i][j], i=(r&3)+8*(r>>2)+4*h (row within group), j=cg*M/2+jt*32+m
    const int rbase = blockIdx.x * 64 + rg * 32;
#pragma unroll
    for (int jt = 0; jt < TJ; ++jt) {
        const int j = cg * (M / 2) + jt * 32 + m;
#pragma unroll
        for (int r = 0; r < 16; ++r) {
            const int orow = rbase + (r & 3) + 8 * (r >> 2) + 4 * h;
            if (orow < N) {
                float v = acc[jt][r];
                if (RELU) v = fmaxf(v, 0.f);
                Y[(size_t)orow * M + j] = v;
            }
        }
    }
}

// --------------------------- fused GATv2 layer -----------------------------
// One wave per node, both heads; depth-2 pipelined fs[src] gather feeding
// logit + online-softmax aggregation.
__global__ void gat_fused_kernel(const float* __restrict__ fs, const float* __restrict__ fd,
                                 const float* __restrict__ attn,
                                 const int* __restrict__ row_off,
                                 const int* __restrict__ srcs,
                                 float* __restrict__ outp) {
    const int wv = threadIdx.x >> 6, l = threadIdx.x & 63;
    const int n = blockIdx.x * 4 + wv;
    if (n >= N_NODES) return;
    const int base = (l >> 5) * 128 + (l & 31) * 4;    // h*128 + d
    const float4 fdv = *reinterpret_cast<const float4*>(&fd[n * 256 + base]);
    const float4 av  = *reinterpret_cast<const float4*>(&attn[base]);
    const int s0 = row_off[n], s1 = row_off[n + 1];

    float m = -INFINITY, lsum = 0.f;
    float4 acc = {0.f, 0.f, 0.f, 0.f};
    float4 v0, v1;
    if (s0 < s1)
        v0 = *reinterpret_cast<const float4*>(&fs[(size_t)srcs[s0] * 256 + base]);
    if (s0 + 1 < s1)
        v1 = *reinterpret_cast<const float4*>(&fs[(size_t)srcs[s0 + 1] * 256 + base]);
    for (int i = s0; i < s1; ++i) {
        const float4 vc = v0;
        v0 = v1;
        if (i + 2 < s1)                                  // depth-2 pipeline
            v1 = *reinterpret_cast<const float4*>(&fs[(size_t)srcs[i + 2] * 256 + base]);
        float p = lrelu(vc.x + fdv.x) * av.x;
        p = fmaf(lrelu(vc.y + fdv.y), av.y, p);
        p = fmaf(lrelu(vc.z + fdv.z), av.z, p);
        p = fmaf(lrelu(vc.w + fdv.w), av.w, p);
#pragma unroll
        for (int off = 1; off < 32; off <<= 1) p += __shfl_xor(p, off);
        const float mn = fmaxf(m, p);
        const float alpha = __expf(m - mn);              // first iter: exp(-inf)=0
        const float w = __expf(p - mn);
        lsum = fmaf(lsum, alpha, w);
        acc.x = fmaf(acc.x, alpha, w * vc.x);
        acc.y = fmaf(acc.y, alpha, w * vc.y);
        acc.z = fmaf(acc.z, alpha, w * vc.z);
        acc.w = fmaf(acc.w, alpha, w * vc.w);
        m = mn;
    }
    const float inv = (s1 > s0) ? 1.f / lsum : 0.f;
    float4 o;
    o.x = fmaxf(acc.x * inv, 0.f);
    o.y = fmaxf(acc.y * inv, 0.f);
    o.z = fmaxf(acc.z * inv, 0.f);
    o.w = fmaxf(acc.w * inv, 0.f);
    *reinterpret_cast<float4*>(&outp[n * 256 + base]) = o;
}

// ------------------------------ fused EdgeMLP ------------------------------
// (unchanged from R4) dst-sorted edges, split-fp16 MFMA layer-1, folded layer-2.
__global__ __launch_bounds__(256, 4) void edge_mlp3_kernel(
    const float* __restrict__ S, const float* __restrict__ Dn,
    const int* __restrict__ srcs, const int* __restrict__ eidx,
    const int* __restrict__ dstf,
    const _Float16* __restrict__ WpH, const _Float16* __restrict__ WpL,
    const float* __restrict__ b1, const float* __restrict__ w2,
    const float* __restrict__ b2, float* __restrict__ out) {
    __shared__ float q[2][64];
    const int tid = threadIdx.x;
    const int wv  = tid >> 6;
    const int l   = tid & 63;
    const int eg  = wv & 1, jg = wv >> 1;
    const int m   = l & 31;
    const int h   = l >> 5;
    const int e0  = blockIdx.x * 64;
    const int slot = e0 + eg * 32 + m;
    const float* __restrict__ Srow = S  + (size_t)srcs[slot] * 512;
    const float* __restrict__ Drow = Dn + (size_t)dstf[eidx[slot]] * 512;
    const half8* __restrict__ BH = reinterpret_cast<const half8*>(WpH);
    const half8* __restrict__ BL = reinterpret_cast<const half8*>(WpL);

    f32x16 acc[4];
#pragma unroll
    for (int jt = 0; jt < 4; ++jt) {
        const float bv = b1[jg * 128 + jt * 32 + m];
#pragma unroll
        for (int r = 0; r < 16; ++r) acc[jt][r] = bv;
    }

    float4 sa = *reinterpret_cast<const float4*>(Srow + h * 8);
    float4 sb = *reinterpret_cast<const float4*>(Srow + h * 8 + 4);
    float4 da = *reinterpret_cast<const float4*>(Drow + h * 8);
    float4 db = *reinterpret_cast<const float4*>(Drow + h * 8 + 4);

    for (int s = 0; s < 32; ++s) {
        float xs[8] = {sa.x + da.x, sa.y + da.y, sa.z + da.z, sa.w + da.w,
                       sb.x + db.x, sb.y + db.y, sb.z + db.z, sb.w + db.w};
        if (s < 31) {
            const int ko = (s + 1) * 16 + h * 8;
            sa = *reinterpret_cast<const float4*>(Srow + ko);
            sb = *reinterpret_cast<const float4*>(Srow + ko + 4);
            da = *reinterpret_cast<const float4*>(Drow + ko);
            db = *reinterpret_cast<const float4*>(Drow + ko + 4);
        }
        half8 ah, al;
#pragma unroll
        for (int i = 0; i < 8; ++i) {
            const float xv = fmaxf(xs[i], 0.f);
            const _Float16 hi = (_Float16)xv;
            ah[i] = hi;
            al[i] = (_Float16)(xv - (float)hi);
        }
#pragma unroll
        for (int jt = 0; jt < 4; ++jt) {
            const int fi = (s * 8 + jg * 4 + jt) * 64 + l;
            const half8 bh = BH[fi];
            const half8 bl = BL[fi];
            acc[jt] = __builtin_amdgcn_mfma_f32_32x32x16_f16(ah, bh, acc[jt], 0, 0, 0);
            acc[jt] = __builtin_amdgcn_mfma_f32_32x32x16_f16(al, bh, acc[jt], 0, 0, 0);
            acc[jt] = __builtin_amdgcn_mfma_f32_32x32x16_f16(ah, bl, acc[jt], 0, 0, 0);
        }
    }

    float part[16];
#pragma unroll
    for (int r = 0; r < 16; ++r) part[r] = 0.f;
#pragma unroll
    for (int jt = 0; jt < 4; ++jt) {
        const float w2v = w2[jg * 128 + jt * 32 + m];
#pragma unroll
        for (int r = 0; r < 16; ++r)
            part[r] = fmaf(fmaxf(acc[jt][r], 0.f), w2v, part[r]);
    }
#pragma unroll
    for (int off = 1; off < 32; off <<= 1)
#pragma unroll
        for (int r = 0; r < 16; ++r) part[r] += __shfl_xor(part[r], off);
    if (m == 0) {
#pragma unroll
        for (int r = 0; r < 16; ++r) {
            const int row = (r & 3) + 8 * (r >> 2) + 4 * h;
            q[jg][eg * 32 + row] = part[r];
        }
    }
    __syncthreads();
    if (tid < 64) out[eidx[e0 + tid]] = q[0][tid] + q[1][tid] + b2[0];
}

// ------------------------------ launch ------------------------------------
extern "C" void kernel_launch(void* const* d_in, const int* in_sizes, int n_in,
                              void* d_out, int out_size, void* d_ws, size_t ws_size,
                              hipStream_t stream) {
    (void)in_sizes; (void)n_in; (void)out_size; (void)ws_size;
    const float* x    = (const float*)d_in[0];
    const int*   src  = (const int*)d_in[1];
    const int*   dst  = (const int*)d_in[2];
    const float* nw0  = (const float*)d_in[3];
    const float* nb0  = (const float*)d_in[4];
    const float* nw1  = (const float*)d_in[5];
    const float* nb1  = (const float*)d_in[6];
    const float* g1ws = (const float*)d_in[7];
    const float* g1bs = (const float*)d_in[8];
    const float* g1wd = (const float*)d_in[9];
    const float* g1bd = (const float*)d_in[10];
    const float* g1a  = (const float*)d_in[11];
    const float* g2ws = (const float*)d_in[12];
    const float* g2bs = (const float*)d_in[13];
    const float* g2wd = (const float*)d_in[14];
    const float* g2bd = (const float*)d_in[15];
    const float* g2a  = (const float*)d_in[16];
    const float* ew0  = (const float*)d_in[17];
    const float* eb0  = (const float*)d_in[18];
    const float* ew1  = (const float*)d_in[19];
    const float* eb1  = (const float*)d_in[20];
    const float* ew2  = (const float*)d_in[21];
    const float* eb2  = (const float*)d_in[22];
    float* out = (float*)d_out;

    float* wsF = (float*)d_ws;
    float* h1  = wsF;                       // 20000*128
    float* g2o = wsF + 2560000;             // 20000*256
    float* fsb = wsF + 7680000;             // 20000*256
    float* fdb = wsF + 12800000;            // 20000*256
    float* g1o = wsF + 17920000;            // 20000*256
    float* Sb  = wsF + 7680000;             // 20000*512 overlays fsb+fdb (dead)
    float* Db  = wsF + 17920000;            // 20000*512 overlays g1o (dead) + fresh
    int* wsI     = (int*)(wsF + 28160000);
    int* row_off = wsI;                     // [0, 20016)
    int* cursor  = wsI + 20016;             // [20016, 40032)
    int* eidx    = wsI + 40032;             // [40032, 360032)
    int* srcs    = wsI + 360032;            // [360032, 680032)
    int* bsum    = wsI + 680032;            // [680032, 680288)
    // ---- dedicated B-fragment pack region (tail), halves ----
    _Float16* pk = (_Float16*)((char*)d_ws + 115361280);
    _Float16* W1H  = pk;               _Float16* W1L  = pk + 131072;   // ew1 512x256
    _Float16* G2SH = pk + 262144;      _Float16* G2SL = pk + 327680;   // g2ws 256x256
    _Float16* G2DH = pk + 393216;      _Float16* G2DL = pk + 458752;   // g2wd
    _Float16* SWH  = pk + 524288;      _Float16* SWL  = pk + 720896;   // ew0-S 384x512
    _Float16* DWH  = pk + 917504;      _Float16* DWL  = pk + 1114112;  // ew0-D
    _Float16* N0H  = pk + 1310720;     _Float16* N0L  = pk + 1318912;  // nw0 64x128
    _Float16* N1H  = pk + 1327104;     _Float16* N1L  = pk + 1343488;  // nw1 128x128
    _Float16* G1SH = pk + 1359872;     _Float16* G1SL = pk + 1376256;  // g1ws 64x256
    _Float16* G1DH = pk + 1392640;     _Float16* G1DL = pk + 1408  *1024; // g1wd

    // ---- CSR build (edges grouped by dst) ----
    hipMemsetAsync(cursor, 0, N_NODES * sizeof(int), stream);
    hist_kernel<<<1250, 256, 0, stream>>>(dst, cursor);
    scan1_kernel<<<NBLK, 256, 0, stream>>>(cursor, row_off, bsum);
    scan2_kernel<<<1, 128, 0, stream>>>(bsum);
    scan3_kernel<<<NBLK, 256, 0, stream>>>(row_off, bsum, cursor);
    scatter_kernel<<<1250, 256, 0, stream>>>(src, dst, cursor, eidx, srcs);

    // ---- weight prepacks (read-only inputs; run up front) ----
    prepack_kernel<512, 256><<<64, 256, 0, stream>>>(ew1, 0, 512, 0, W1H, W1L);
    prepack_kernel<256, 256><<<32, 256, 0, stream>>>(g2ws, 0, 256, 0, G2SH, G2SL);
    prepack_kernel<256, 256><<<32, 256, 0, stream>>>(g2wd, 0, 256, 0, G2DH, G2DL);
    prepack_kernel<384, 512><<<96, 256, 0, stream>>>(ew0, 0, 128, 256, SWH, SWL);
    prepack_kernel<384, 512><<<96, 256, 0, stream>>>(ew0, 128, 128, 512, DWH, DWL);
    prepack_kernel<64, 128><<<4, 256, 0, stream>>>(nw0, 0, 64, 0, N0H, N0L);
    prepack_kernel<128, 128><<<8, 256, 0, stream>>>(nw1, 0, 128, 0, N1H, N1L);
    prepack_kernel<64, 256><<<8, 256, 0, stream>>>(g1ws, 0, 64, 0, G1SH, G1SL);
    prepack_kernel<64, 256><<<8, 256, 0, stream>>>(g1wd, 0, 64, 0, G1DH, G1DL);

    constexpr int GB = (N_NODES + 63) / 64;   // 313

    // ---- NodeMLP: fsb(N,128) = relu(x@nw0+b); h1 = relu(fsb@nw1+b) ----
    mfma_linear_kernel<64, 128, 64, 64, 64, true, true, 4>
        <<<GB, 256, 0, stream>>>(x, x, N0H, N0L, nb0, fsb, N_NODES);
    mfma_linear_kernel<128, 128, 128, 128, 128, true, true, 4>
        <<<GB, 256, 0, stream>>>(fsb, fsb, N1H, N1L, nb1, h1, N_NODES);

    // ---- GATv2 layer 1 ----
    mfma_linear_kernel<64, 256, 64, 64, 64, true, false, 4>
        <<<GB, 256, 0, stream>>>(x, x, G1SH, G1SL, g1bs, fsb, N_NODES);
    mfma_linear_kernel<64, 256, 64, 64, 64, true, false, 4>
        <<<GB, 256, 0, stream>>>(x, x, G1DH, G1DL, g1bd, fdb, N_NODES);
    gat_fused_kernel<<<5000, 256, 0, stream>>>(fsb, fdb, g1a, row_off, srcs, g1o);

    // ---- GATv2 layer 2 ----
    mfma_linear_kernel<256, 256, 256, 256, 256, true, false, 4>
        <<<GB, 256, 0, stream>>>(g1o, g1o, G2SH, G2SL, g2bs, fsb, N_NODES);
    mfma_linear_kernel<256, 256, 256, 256, 256, true, false, 4>
        <<<GB, 256, 0, stream>>>(g1o, g1o, G2DH, G2DL, g2bd, fdb, N_NODES);
    gat_fused_kernel<<<5000, 256, 0, stream>>>(fsb, fdb, g2a, row_off, srcs, g2o);

    // ---- S/D precompute (EdgeMLP layer-0 decomposition) ----
    mfma_linear_kernel<384, 512, 128, 128, 256, false, false, 2>
        <<<GB, 256, 0, stream>>>(h1, g2o, SWH, SWL, nullptr, Sb, N_NODES);
    mfma_linear_kernel<384, 512, 128, 128, 256, true, false, 2>
        <<<GB, 256, 0, stream>>>(h1, g2o, DWH, DWL, eb0, Db, N_NODES);

    // ---- fused EdgeMLP ----
    edge_mlp3_kernel<<<N_EDGES / 64, 256, 0, stream>>>(Sb, Db, srcs, eidx, dst,
                                                       W1H, W1L, eb1, ew2, eb2, out);
}

// Round 6
// 729.454 us; speedup vs baseline: 8.4358x; 1.1337x over previous
//
#include <hip/hip_runtime.h>
#include <hip/hip_bf16.h>

// ---------------------------------------------------------------------------
// EdgePredModel: NodeMLP + 2x GATv2 + EdgeMLP.
// R6: edge MLP restructured (edge_mlp4): 128 edges/block, wave = 32e x 256j
//     (TJ=8), B fragments LDS-staged once per block (double-buffered),
//     4x cut in B L2 traffic + 2x cut in S/D gather. Node side unchanged.
// ---------------------------------------------------------------------------
constexpr int N_NODES = 20000;
constexpr int N_EDGES = 320000;
constexpr int NBLK    = (N_NODES + 255) / 256;   // 79 (scan blocks)

typedef _Float16 half8 __attribute__((ext_vector_type(8)));
typedef float    f32x16 __attribute__((ext_vector_type(16)));

__device__ __forceinline__ float lrelu(float x) { return x > 0.f ? x : 0.2f * x; }

// ------------------------------ CSR build ---------------------------------
__global__ void hist_kernel(const int* __restrict__ dst, int* __restrict__ counts) {
    int e = blockIdx.x * 256 + threadIdx.x;
    if (e < N_EDGES) atomicAdd(&counts[dst[e]], 1);
}

__global__ void scan1_kernel(const int* __restrict__ counts, int* __restrict__ partial,
                             int* __restrict__ bsum) {
    __shared__ int s[256];
    int i = blockIdx.x * 256 + threadIdx.x;
    int v = (i < N_NODES) ? counts[i] : 0;
    s[threadIdx.x] = v;
    __syncthreads();
    for (int off = 1; off < 256; off <<= 1) {
        int t = (threadIdx.x >= off) ? s[threadIdx.x - off] : 0;
        __syncthreads();
        s[threadIdx.x] += t;
        __syncthreads();
    }
    if (i < N_NODES) partial[i] = s[threadIdx.x] - v;     // exclusive within block
    if (threadIdx.x == 255) bsum[blockIdx.x] = s[255];    // block total
}

__global__ void scan2_kernel(int* __restrict__ bsum) {
    __shared__ int s[128];
    int b = threadIdx.x;
    int v = (b < NBLK) ? bsum[b] : 0;
    s[b] = v;
    __syncthreads();
    for (int off = 1; off < 128; off <<= 1) {
        int t = (b >= off) ? s[b - off] : 0;
        __syncthreads();
        s[b] += t;
        __syncthreads();
    }
    if (b < NBLK) bsum[128 + b] = s[b] - v;               // exclusive block offsets
}

__global__ void scan3_kernel(int* __restrict__ row_off, const int* __restrict__ bsum,
                             int* __restrict__ cursor) {
    int i = blockIdx.x * 256 + threadIdx.x;
    if (i < N_NODES) {
        int v = row_off[i] + bsum[128 + blockIdx.x];
        row_off[i] = v;
        cursor[i]  = v;
    }
    if (i == 0) row_off[N_NODES] = N_EDGES;
}

__global__ void scatter_kernel(const int* __restrict__ src, const int* __restrict__ dst,
                               int* __restrict__ cursor, int* __restrict__ eidx,
                               int* __restrict__ srcs) {
    int e = blockIdx.x * 256 + threadIdx.x;
    if (e < N_EDGES) {
        int p = atomicAdd(&cursor[dst[e]], 1);
        eidx[p] = e;
        srcs[p] = src[e];
    }
}

// --------------------- generic W prepack into B-fragments ------------------
template <int K, int M>
__global__ void prepack_kernel(const float* __restrict__ W, int r1, int k1, int r2,
                               _Float16* __restrict__ WpH, _Float16* __restrict__ WpL) {
    const int idx = blockIdx.x * 256 + threadIdx.x;
    if (idx >= (K / 16) * (M / 32) * 64) return;
    const int l  = idx & 63;
    const int t  = (idx >> 6) % (M / 32);
    const int s  = (idx >> 6) / (M / 32);
    const int j  = t * 32 + (l & 31);
    const int kb = s * 16 + (l >> 5) * 8;
    half8 vh, vl;
#pragma unroll
    for (int i = 0; i < 8; ++i) {
        const int k    = kb + i;
        const int rrow = (k < k1) ? (r1 + k) : (r2 + (k - k1));
        const float w  = W[(size_t)rrow * M + j];
        const _Float16 h = (_Float16)w;
        vh[i] = h;
        vl[i] = (_Float16)(w - (float)h);
    }
    reinterpret_cast<half8*>(WpH)[idx] = vh;
    reinterpret_cast<half8*>(WpL)[idx] = vl;
}

// ----------------------- split-fp16 MFMA node linear -----------------------
template <int K, int M, int K1, int LD1, int LD2, bool HASB, bool RELU, int MINW>
__global__ __launch_bounds__(256, MINW) void mfma_linear_kernel(
    const float* __restrict__ X1, const float* __restrict__ X2,
    const _Float16* __restrict__ BHp, const _Float16* __restrict__ BLp,
    const float* __restrict__ bias, float* __restrict__ Y, int N) {
    constexpr int TJ = M / 64;              // col tiles per wave
    const int tid = threadIdx.x;
    const int wv  = tid >> 6, l = tid & 63;
    const int rg  = wv & 1, cg = wv >> 1;
    const int m   = l & 31, h = l >> 5;
    const int row = blockIdx.x * 64 + rg * 32 + m;
    const int ar  = (row < N) ? row : (N - 1);
    const float* __restrict__ xr1 = X1 + (size_t)ar * LD1;
    const float* __restrict__ xr2 = X2 + (size_t)ar * LD2;
    const half8* __restrict__ BH = reinterpret_cast<const half8*>(BHp);
    const half8* __restrict__ BL = reinterpret_cast<const half8*>(BLp);

    f32x16 acc[TJ];
#pragma unroll
    for (int jt = 0; jt < TJ; ++jt) {
        const float bv = HASB ? bias[cg * (M / 2) + jt * 32 + m] : 0.f;
#pragma unroll
        for (int r = 0; r < 16; ++r) acc[jt][r] = bv;
    }

    const int kf = h * 8;
    const float* pf = (kf < K1) ? (xr1 + kf) : (xr2 + (kf - K1));
    float4 xa = *reinterpret_cast<const float4*>(pf);
    float4 xb = *reinterpret_cast<const float4*>(pf + 4);

    for (int s = 0; s < K / 16; ++s) {
        const float xs[8] = {xa.x, xa.y, xa.z, xa.w, xb.x, xb.y, xb.z, xb.w};
        if (s + 1 < K / 16) {
            const int kn = (s + 1) * 16 + h * 8;
            const float* pn = (kn < K1) ? (xr1 + kn) : (xr2 + (kn - K1));
            xa = *reinterpret_cast<const float4*>(pn);
            xb = *reinterpret_cast<const float4*>(pn + 4);
        }
        half8 ah, al;
#pragma unroll
        for (int i = 0; i < 8; ++i) {
            const _Float16 hi = (_Float16)xs[i];
            ah[i] = hi;
            al[i] = (_Float16)(xs[i] - (float)hi);
        }
#pragma unroll
        for (int jt = 0; jt < TJ; ++jt) {
            const int fi = (s * (M / 32) + cg * TJ + jt) * 64 + l;
            const half8 bh = BH[fi];
            const half8 bl = BL[fi];
            acc[jt] = __builtin_amdgcn_mfma_f32_32x32x16_f16(ah, bh, acc[jt], 0, 0, 0);
            acc[jt] = __builtin_amdgcn_mfma_f32_32x32x16_f16(al, bh, acc[jt], 0, 0, 0);
            acc[jt] = __builtin_amdgcn_mfma_f32_32x32x16_f16(ah, bl, acc[jt], 0, 0, 0);
        }
    }

    const int rbase = blockIdx.x * 64 + rg * 32;
#pragma unroll
    for (int jt = 0; jt < TJ; ++jt) {
        const int j = cg * (M / 2) + jt * 32 + m;
#pragma unroll
        for (int r = 0; r < 16; ++r) {
            const int orow = rbase + (r & 3) + 8 * (r >> 2) + 4 * h;
            if (orow < N) {
                float v = acc[jt][r];
                if (RELU) v = fmaxf(v, 0.f);
                Y[(size_t)orow * M + j] = v;
            }
        }
    }
}

// --------------------------- fused GATv2 layer -----------------------------
__global__ void gat_fused_kernel(const float* __restrict__ fs, const float* __restrict__ fd,
                                 const float* __restrict__ attn,
                                 const int* __restrict__ row_off,
                                 const int* __restrict__ srcs,
                                 float* __restrict__ outp) {
    const int wv = threadIdx.x >> 6, l = threadIdx.x & 63;
    const int n = blockIdx.x * 4 + wv;
    if (n >= N_NODES) return;
    const int base = (l >> 5) * 128 + (l & 31) * 4;    // h*128 + d
    const float4 fdv = *reinterpret_cast<const float4*>(&fd[n * 256 + base]);
    const float4 av  = *reinterpret_cast<const float4*>(&attn[base]);
    const int s0 = row_off[n], s1 = row_off[n + 1];

    float m = -INFINITY, lsum = 0.f;
    float4 acc = {0.f, 0.f, 0.f, 0.f};
    float4 v0, v1;
    if (s0 < s1)
        v0 = *reinterpret_cast<const float4*>(&fs[(size_t)srcs[s0] * 256 + base]);
    if (s0 + 1 < s1)
        v1 = *reinterpret_cast<const float4*>(&fs[(size_t)srcs[s0 + 1] * 256 + base]);
    for (int i = s0; i < s1; ++i) {
        const float4 vc = v0;
        v0 = v1;
        if (i + 2 < s1)                                  // depth-2 pipeline
            v1 = *reinterpret_cast<const float4*>(&fs[(size_t)srcs[i + 2] * 256 + base]);
        float p = lrelu(vc.x + fdv.x) * av.x;
        p = fmaf(lrelu(vc.y + fdv.y), av.y, p);
        p = fmaf(lrelu(vc.z + fdv.z), av.z, p);
        p = fmaf(lrelu(vc.w + fdv.w), av.w, p);
#pragma unroll
        for (int off = 1; off < 32; off <<= 1) p += __shfl_xor(p, off);
        const float mn = fmaxf(m, p);
        const float alpha = __expf(m - mn);              // first iter: exp(-inf)=0
        const float w = __expf(p - mn);
        lsum = fmaf(lsum, alpha, w);
        acc.x = fmaf(acc.x, alpha, w * vc.x);
        acc.y = fmaf(acc.y, alpha, w * vc.y);
        acc.z = fmaf(acc.z, alpha, w * vc.z);
        acc.w = fmaf(acc.w, alpha, w * vc.w);
        m = mn;
    }
    const float inv = (s1 > s0) ? 1.f / lsum : 0.f;
    float4 o;
    o.x = fmaxf(acc.x * inv, 0.f);
    o.y = fmaxf(acc.y * inv, 0.f);
    o.z = fmaxf(acc.z * inv, 0.f);
    o.w = fmaxf(acc.w * inv, 0.f);
    *reinterpret_cast<float4*>(&outp[n * 256 + base]) = o;
}

// ------------------------------ fused EdgeMLP v4 ---------------------------
// Block = 128 edges, 4 waves; each wave = 32 edges x all 256 j (TJ=8).
// B fragments staged once per block into double-buffered LDS (2 x 16 KB);
// each wave stages 4 of 16 1-KB chunks per k-step (stride-1 b128, no
// conflicts). x = relu(S[src]+D[dst]) split hi/lo in registers. Layer-2
// folded into register epilogue + 32-lane shuffle reduce; scatter via eidx.
__global__ __launch_bounds__(256, 2) void edge_mlp4_kernel(
    const float* __restrict__ S, const float* __restrict__ Dn,
    const int* __restrict__ srcs, const int* __restrict__ eidx,
    const int* __restrict__ dstf,
    const _Float16* __restrict__ WpH, const _Float16* __restrict__ WpL,
    const float* __restrict__ b1, const float* __restrict__ w2,
    const float* __restrict__ b2, float* __restrict__ out) {
    __shared__ __align__(16) _Float16 Bs[2][8][2][512];   // 32 KB
    const int tid = threadIdx.x;
    const int wv  = tid >> 6, l = tid & 63;
    const int m   = l & 31, h = l >> 5;
    const int e0  = blockIdx.x * 128;
    const int slot = e0 + wv * 32 + m;
    const float* __restrict__ Srow = S  + (size_t)srcs[slot] * 512;
    const float* __restrict__ Drow = Dn + (size_t)dstf[eidx[slot]] * 512;

    f32x16 acc[8];
#pragma unroll
    for (int jt = 0; jt < 8; ++jt) {
        const float bv = b1[jt * 32 + m];
#pragma unroll
        for (int r = 0; r < 16; ++r) acc[jt][r] = bv;
    }

    // stage B(s=0) into buf 0: wave wv stages chunks 4wv..4wv+3
#pragma unroll
    for (int c = 0; c < 4; ++c) {
        const int ch = wv * 4 + c, jt = ch >> 1, hb = ch & 1;
        const _Float16* sp = (hb ? WpL : WpH) + ((size_t)jt * 64 + l) * 8;
        *reinterpret_cast<float4*>(&Bs[0][jt][hb][l * 8]) =
            *reinterpret_cast<const float4*>(sp);
    }
    // x prefetch s=0
    float4 sa = *reinterpret_cast<const float4*>(Srow + h * 8);
    float4 sb = *reinterpret_cast<const float4*>(Srow + h * 8 + 4);
    float4 da = *reinterpret_cast<const float4*>(Drow + h * 8);
    float4 db = *reinterpret_cast<const float4*>(Drow + h * 8 + 4);
    __syncthreads();

    for (int s = 0; s < 32; ++s) {
        const int buf = s & 1;
        // issue B-stage loads for s+1 (land in regs; ds_write after compute)
        float4 bst[4];
        if (s < 31) {
#pragma unroll
            for (int c = 0; c < 4; ++c) {
                const int ch = wv * 4 + c, jt = ch >> 1, hb = ch & 1;
                const _Float16* sp =
                    (hb ? WpL : WpH) + ((size_t)((s + 1) * 8 + jt) * 64 + l) * 8;
                bst[c] = *reinterpret_cast<const float4*>(sp);
            }
        }
        const float xs[8] = {sa.x + da.x, sa.y + da.y, sa.z + da.z, sa.w + da.w,
                             sb.x + db.x, sb.y + db.y, sb.z + db.z, sb.w + db.w};
        if (s < 31) {                        // prefetch next x k-octet
            const int ko = (s + 1) * 16 + h * 8;
            sa = *reinterpret_cast<const float4*>(Srow + ko);
            sb = *reinterpret_cast<const float4*>(Srow + ko + 4);
            da = *reinterpret_cast<const float4*>(Drow + ko);
            db = *reinterpret_cast<const float4*>(Drow + ko + 4);
        }
        half8 ah, al;
#pragma unroll
        for (int i = 0; i < 8; ++i) {
            const float xv = fmaxf(xs[i], 0.f);
            const _Float16 hi = (_Float16)xv;
            ah[i] = hi;
            al[i] = (_Float16)(xv - (float)hi);
        }
#pragma unroll
        for (int jt = 0; jt < 8; ++jt) {
            const half8 bh = *reinterpret_cast<const half8*>(&Bs[buf][jt][0][l * 8]);
            const half8 bl = *reinterpret_cast<const half8*>(&Bs[buf][jt][1][l * 8]);
            acc[jt] = __builtin_amdgcn_mfma_f32_32x32x16_f16(ah, bh, acc[jt], 0, 0, 0);
            acc[jt] = __builtin_amdgcn_mfma_f32_32x32x16_f16(al, bh, acc[jt], 0, 0, 0);
            acc[jt] = __builtin_amdgcn_mfma_f32_32x32x16_f16(ah, bl, acc[jt], 0, 0, 0);
        }
        if (s < 31) {
#pragma unroll
            for (int c = 0; c < 4; ++c) {
                const int ch = wv * 4 + c, jt = ch >> 1, hb = ch & 1;
                *reinterpret_cast<float4*>(&Bs[buf ^ 1][jt][hb][l * 8]) = bst[c];
            }
        }
        __syncthreads();
    }

    // ---- layer-2 fold + 32-lane reduce + scatter store ----
    float part[16];
#pragma unroll
    for (int r = 0; r < 16; ++r) part[r] = 0.f;
#pragma unroll
    for (int jt = 0; jt < 8; ++jt) {
        const float w2v = w2[jt * 32 + m];
#pragma unroll
        for (int r = 0; r < 16; ++r)
            part[r] = fmaf(fmaxf(acc[jt][r], 0.f), w2v, part[r]);
    }
#pragma unroll
    for (int off = 1; off < 32; off <<= 1)
#pragma unroll
        for (int r = 0; r < 16; ++r) part[r] += __shfl_xor(part[r], off);
    if (m == 0) {
        const float b2v = b2[0];
#pragma unroll
        for (int r = 0; r < 16; ++r) {
            const int row = (r & 3) + 8 * (r >> 2) + 4 * h;
            out[eidx[e0 + wv * 32 + row]] = part[r] + b2v;
        }
    }
}

// ------------------------------ launch ------------------------------------
extern "C" void kernel_launch(void* const* d_in, const int* in_sizes, int n_in,
                              void* d_out, int out_size, void* d_ws, size_t ws_size,
                              hipStream_t stream) {
    (void)in_sizes; (void)n_in; (void)out_size; (void)ws_size;
    const float* x    = (const float*)d_in[0];
    const int*   src  = (const int*)d_in[1];
    const int*   dst  = (const int*)d_in[2];
    const float* nw0  = (const float*)d_in[3];
    const float* nb0  = (const float*)d_in[4];
    const float* nw1  = (const float*)d_in[5];
    const float* nb1  = (const float*)d_in[6];
    const float* g1ws = (const float*)d_in[7];
    const float* g1bs = (const float*)d_in[8];
    const float* g1wd = (const float*)d_in[9];
    const float* g1bd = (const float*)d_in[10];
    const float* g1a  = (const float*)d_in[11];
    const float* g2ws = (const float*)d_in[12];
    const float* g2bs = (const float*)d_in[13];
    const float* g2wd = (const float*)d_in[14];
    const float* g2bd = (const float*)d_in[15];
    const float* g2a  = (const float*)d_in[16];
    const float* ew0  = (const float*)d_in[17];
    const float* eb0  = (const float*)d_in[18];
    const float* ew1  = (const float*)d_in[19];
    const float* eb1  = (const float*)d_in[20];
    const float* ew2  = (const float*)d_in[21];
    const float* eb2  = (const float*)d_in[22];
    float* out = (float*)d_out;

    float* wsF = (float*)d_ws;
    float* h1  = wsF;                       // 20000*128
    float* g2o = wsF + 2560000;             // 20000*256
    float* fsb = wsF + 7680000;             // 20000*256
    float* fdb = wsF + 12800000;            // 20000*256
    float* g1o = wsF + 17920000;            // 20000*256
    float* Sb  = wsF + 7680000;             // 20000*512 overlays fsb+fdb (dead)
    float* Db  = wsF + 17920000;            // 20000*512 overlays g1o (dead) + fresh
    int* wsI     = (int*)(wsF + 28160000);
    int* row_off = wsI;                     // [0, 20016)
    int* cursor  = wsI + 20016;             // [20016, 40032)
    int* eidx    = wsI + 40032;             // [40032, 360032)
    int* srcs    = wsI + 360032;            // [360032, 680032)
    int* bsum    = wsI + 680032;            // [680032, 680288)
    // ---- dedicated B-fragment pack region (tail), halves ----
    _Float16* pk = (_Float16*)((char*)d_ws + 115361280);
    _Float16* W1H  = pk;               _Float16* W1L  = pk + 131072;   // ew1 512x256
    _Float16* G2SH = pk + 262144;      _Float16* G2SL = pk + 327680;   // g2ws 256x256
    _Float16* G2DH = pk + 393216;      _Float16* G2DL = pk + 458752;   // g2wd
    _Float16* SWH  = pk + 524288;      _Float16* SWL  = pk + 720896;   // ew0-S 384x512
    _Float16* DWH  = pk + 917504;      _Float16* DWL  = pk + 1114112;  // ew0-D
    _Float16* N0H  = pk + 1310720;     _Float16* N0L  = pk + 1318912;  // nw0 64x128
    _Float16* N1H  = pk + 1327104;     _Float16* N1L  = pk + 1343488;  // nw1 128x128
    _Float16* G1SH = pk + 1359872;     _Float16* G1SL = pk + 1376256;  // g1ws 64x256
    _Float16* G1DH = pk + 1392640;     _Float16* G1DL = pk + 1408  *1024; // g1wd

    // ---- CSR build (edges grouped by dst) ----
    hipMemsetAsync(cursor, 0, N_NODES * sizeof(int), stream);
    hist_kernel<<<1250, 256, 0, stream>>>(dst, cursor);
    scan1_kernel<<<NBLK, 256, 0, stream>>>(cursor, row_off, bsum);
    scan2_kernel<<<1, 128, 0, stream>>>(bsum);
    scan3_kernel<<<NBLK, 256, 0, stream>>>(row_off, bsum, cursor);
    scatter_kernel<<<1250, 256, 0, stream>>>(src, dst, cursor, eidx, srcs);

    // ---- weight prepacks (read-only inputs; run up front) ----
    prepack_kernel<512, 256><<<64, 256, 0, stream>>>(ew1, 0, 512, 0, W1H, W1L);
    prepack_kernel<256, 256><<<32, 256, 0, stream>>>(g2ws, 0, 256, 0, G2SH, G2SL);
    prepack_kernel<256, 256><<<32, 256, 0, stream>>>(g2wd, 0, 256, 0, G2DH, G2DL);
    prepack_kernel<384, 512><<<96, 256, 0, stream>>>(ew0, 0, 128, 256, SWH, SWL);
    prepack_kernel<384, 512><<<96, 256, 0, stream>>>(ew0, 128, 128, 512, DWH, DWL);
    prepack_kernel<64, 128><<<4, 256, 0, stream>>>(nw0, 0, 64, 0, N0H, N0L);
    prepack_kernel<128, 128><<<8, 256, 0, stream>>>(nw1, 0, 128, 0, N1H, N1L);
    prepack_kernel<64, 256><<<8, 256, 0, stream>>>(g1ws, 0, 64, 0, G1SH, G1SL);
    prepack_kernel<64, 256><<<8, 256, 0, stream>>>(g1wd, 0, 64, 0, G1DH, G1DL);

    constexpr int GB = (N_NODES + 63) / 64;   // 313

    // ---- NodeMLP: fsb(N,128) = relu(x@nw0+b); h1 = relu(fsb@nw1+b) ----
    mfma_linear_kernel<64, 128, 64, 64, 64, true, true, 4>
        <<<GB, 256, 0, stream>>>(x, x, N0H, N0L, nb0, fsb, N_NODES);
    mfma_linear_kernel<128, 128, 128, 128, 128, true, true, 4>
        <<<GB, 256, 0, stream>>>(fsb, fsb, N1H, N1L, nb1, h1, N_NODES);

    // ---- GATv2 layer 1 ----
    mfma_linear_kernel<64, 256, 64, 64, 64, true, false, 4>
        <<<GB, 256, 0, stream>>>(x, x, G1SH, G1SL, g1bs, fsb, N_NODES);
    mfma_linear_kernel<64, 256, 64, 64, 64, true, false, 4>
        <<<GB, 256, 0, stream>>>(x, x, G1DH, G1DL, g1bd, fdb, N_NODES);
    gat_fused_kernel<<<5000, 256, 0, stream>>>(fsb, fdb, g1a, row_off, srcs, g1o);

    // ---- GATv2 layer 2 ----
    mfma_linear_kernel<256, 256, 256, 256, 256, true, false, 4>
        <<<GB, 256, 0, stream>>>(g1o, g1o, G2SH, G2SL, g2bs, fsb, N_NODES);
    mfma_linear_kernel<256, 256, 256, 256, 256, true, false, 4>
        <<<GB, 256, 0, stream>>>(g1o, g1o, G2DH, G2DL, g2bd, fdb, N_NODES);
    gat_fused_kernel<<<5000, 256, 0, stream>>>(fsb, fdb, g2a, row_off, srcs, g2o);

    // ---- S/D precompute (EdgeMLP layer-0 decomposition) ----
    mfma_linear_kernel<384, 512, 128, 128, 256, false, false, 2>
        <<<GB, 256, 0, stream>>>(h1, g2o, SWH, SWL, nullptr, Sb, N_NODES);
    mfma_linear_kernel<384, 512, 128, 128, 256, true, false, 2>
        <<<GB, 256, 0, stream>>>(h1, g2o, DWH, DWL, eb0, Db, N_NODES);

    // ---- fused EdgeMLP v4 ----
    edge_mlp4_kernel<<<N_EDGES / 128, 256, 0, stream>>>(Sb, Db, srcs, eidx, dst,
                                                        W1H, W1L, eb1, ew2, eb2, out);
}

// Round 7
// 670.929 us; speedup vs baseline: 9.1716x; 1.0872x over previous
//
#include <hip/hip_runtime.h>
#include <hip/hip_bf16.h>

// ---------------------------------------------------------------------------
// EdgePredModel: NodeMLP + 2x GATv2 + EdgeMLP.
// R7: node-side consolidation (fused fc pairs + fused S/D via j-block grid,
//     merged prepack, single-block scan) + edge_mlp5 (quad-buffered B,
//     barrier per 2 k-steps, pair-wise x prefetch).
// ---------------------------------------------------------------------------
constexpr int N_NODES = 20000;
constexpr int N_EDGES = 320000;

typedef _Float16 half8 __attribute__((ext_vector_type(8)));
typedef float    f32x16 __attribute__((ext_vector_type(16)));

__device__ __forceinline__ float lrelu(float x) { return x > 0.f ? x : 0.2f * x; }

// ------------------------------ CSR build ---------------------------------
__global__ void hist_kernel(const int* __restrict__ dst, int* __restrict__ counts) {
    int e = blockIdx.x * 256 + threadIdx.x;
    if (e < N_EDGES) atomicAdd(&counts[dst[e]], 1);
}

// single-block exclusive scan of 20000 counts -> row_off, cursor
__global__ void scan_all_kernel(const int* __restrict__ counts,
                                int* __restrict__ row_off, int* __restrict__ cursor) {
    __shared__ int ps[1024];
    const int t = threadIdx.x;
    const int base = t * 20;
    int loc[20];
    int sum = 0;
#pragma unroll
    for (int i = 0; i < 20; ++i) {
        const int idx = base + i;
        const int v = (idx < N_NODES) ? counts[idx] : 0;
        loc[i] = sum;
        sum += v;
    }
    ps[t] = sum;
    __syncthreads();
    for (int off = 1; off < 1024; off <<= 1) {
        const int v = (t >= off) ? ps[t - off] : 0;
        __syncthreads();
        ps[t] += v;
        __syncthreads();
    }
    const int ex = ps[t] - sum;     // exclusive prefix of this thread's chunk
#pragma unroll
    for (int i = 0; i < 20; ++i) {
        const int idx = base + i;
        if (idx < N_NODES) {
            row_off[idx] = ex + loc[i];
            cursor[idx]  = ex + loc[i];
        }
    }
    if (t == 0) row_off[N_NODES] = N_EDGES;
}

__global__ void scatter_kernel(const int* __restrict__ src, const int* __restrict__ dst,
                               int* __restrict__ cursor, int* __restrict__ eidx,
                               int* __restrict__ srcs) {
    int e = blockIdx.x * 256 + threadIdx.x;
    if (e < N_EDGES) {
        int p = atomicAdd(&cursor[dst[e]], 1);
        eidx[p] = e;
        srcs[p] = src[e];
    }
}

// --------------------- merged W prepack into B-fragments -------------------
// Fragment layout per 256(or 128)-col slice: fi=(s*(M/32)+t)*64+l; lane l
// holds B[k=s*16+(l>>5)*8+i][j=t*32+(l&31)].
template <int K, int M>
__device__ __forceinline__ void pack_one(int idx, const float* __restrict__ W,
                                         int r1, int k1, int r2, int joff, int ldw,
                                         _Float16* __restrict__ H,
                                         _Float16* __restrict__ L) {
    const int l  = idx & 63;
    const int t  = (idx >> 6) % (M / 32);
    const int s  = (idx >> 6) / (M / 32);
    const int j  = joff + t * 32 + (l & 31);
    const int kb = s * 16 + (l >> 5) * 8;
    half8 vh, vl;
#pragma unroll
    for (int i = 0; i < 8; ++i) {
        const int k    = kb + i;
        const int rrow = (k < k1) ? (r1 + k) : (r2 + (k - k1));
        const float w  = W[(size_t)rrow * ldw + j];
        const _Float16 h = (_Float16)w;
        vh[i] = h;
        vl[i] = (_Float16)(w - (float)h);
    }
    reinterpret_cast<half8*>(H)[idx] = vh;
    reinterpret_cast<half8*>(L)[idx] = vl;
}

// segment offsets in half8 units
constexpr int OFF_W1  = 0;        // ew1  512x256 -> 16384
constexpr int OFF_G1S = 16384;    // g1ws  64x256 ->  2048
constexpr int OFF_G1D = 18432;
constexpr int OFF_G2S = 20480;    // g2ws 256x256 ->  8192
constexpr int OFF_G2D = 28672;
constexpr int OFF_SW0 = 36864;    // ew0-S cols 0-255   -> 12288
constexpr int OFF_SW1 = 49152;    // ew0-S cols 256-511
constexpr int OFF_DW0 = 61440;    // ew0-D cols 0-255
constexpr int OFF_DW1 = 73728;
constexpr int OFF_N0  = 86016;    // nw0 64x128 -> 1024
constexpr int OFF_N1  = 87040;    // nw1 128x128 -> 2048
constexpr int PACK_TOT = 89088;   // total half8

struct PackIn {
    const float *ew1, *g1ws, *g1wd, *g2ws, *g2wd, *ew0, *nw0, *nw1;
    _Float16 *H, *L;
};

__global__ void prepack_all_kernel(PackIn a) {
    const int idx = blockIdx.x * 256 + threadIdx.x;
    if (idx >= PACK_TOT) return;
    _Float16* H = a.H;
    _Float16* L = a.L;
    if (idx < OFF_G1S)
        pack_one<512, 256>(idx - OFF_W1, a.ew1, 0, 512, 0, 0, 256,
                           H + OFF_W1 * 8, L + OFF_W1 * 8);
    else if (idx < OFF_G1D)
        pack_one<64, 256>(idx - OFF_G1S, a.g1ws, 0, 64, 0, 0, 256,
                          H + OFF_G1S * 8, L + OFF_G1S * 8);
    else if (idx < OFF_G2S)
        pack_one<64, 256>(idx - OFF_G1D, a.g1wd, 0, 64, 0, 0, 256,
                          H + OFF_G1D * 8, L + OFF_G1D * 8);
    else if (idx < OFF_G2D)
        pack_one<256, 256>(idx - OFF_G2S, a.g2ws, 0, 256, 0, 0, 256,
                           H + OFF_G2S * 8, L + OFF_G2S * 8);
    else if (idx < OFF_SW0)
        pack_one<256, 256>(idx - OFF_G2D, a.g2wd, 0, 256, 0, 0, 256,
                           H + OFF_G2D * 8, L + OFF_G2D * 8);
    else if (idx < OFF_SW1)
        pack_one<384, 256>(idx - OFF_SW0, a.ew0, 0, 128, 256, 0, 512,
                           H + OFF_SW0 * 8, L + OFF_SW0 * 8);
    else if (idx < OFF_DW0)
        pack_one<384, 256>(idx - OFF_SW1, a.ew0, 0, 128, 256, 256, 512,
                           H + OFF_SW1 * 8, L + OFF_SW1 * 8);
    else if (idx < OFF_DW1)
        pack_one<384, 256>(idx - OFF_DW0, a.ew0, 128, 128, 512, 0, 512,
                           H + OFF_DW0 * 8, L + OFF_DW0 * 8);
    else if (idx < OFF_N0)
        pack_one<384, 256>(idx - OFF_DW1, a.ew0, 128, 128, 512, 256, 512,
                           H + OFF_DW1 * 8, L + OFF_DW1 * 8);
    else if (idx < OFF_N1)
        pack_one<64, 128>(idx - OFF_N0, a.nw0, 0, 64, 0, 0, 128,
                          H + OFF_N0 * 8, L + OFF_N0 * 8);
    else
        pack_one<128, 128>(idx - OFF_N1, a.nw1, 0, 128, 0, 0, 128,
                           H + OFF_N1 * 8, L + OFF_N1 * 8);
}

// ----------------------- split-fp16 MFMA node linear -----------------------
// grid = (row_blocks, NJB). Block covers 32*WR rows x (WC*TJ*32) cols of the
// jb-th column segment. Per-jb output pointer / bias pointer in LinOut.
struct LinOut { float* y[4]; const float* b[4]; };

template <int K, int TJ, int WR, int K1, int LD1, int LD2, int LDY,
          bool RELU, int MINW, int SEG>
__global__ __launch_bounds__(256, MINW) void mfma_linear2_kernel(
    const float* __restrict__ X1, const float* __restrict__ X2,
    const _Float16* __restrict__ BHp, const _Float16* __restrict__ BLp,
    LinOut lo, int N) {
    constexpr int WC    = 4 / WR;
    constexpr int TILES = WC * TJ;
    const int jb  = blockIdx.y;
    const int tid = threadIdx.x;
    const int wv  = tid >> 6, l = tid & 63;
    const int rg  = (WR == 1) ? 0 : (wv & 1);
    const int cg  = (WR == 1) ? wv : (wv >> 1);
    const int m   = l & 31, h = l >> 5;
    const int row = blockIdx.x * (32 * WR) + rg * 32 + m;
    const int ar  = (row < N) ? row : (N - 1);
    const float* __restrict__ xr1 = X1 + (size_t)ar * LD1;
    const float* __restrict__ xr2 = X2 + (size_t)ar * LD2;
    const half8* __restrict__ BH = reinterpret_cast<const half8*>(BHp) + (size_t)jb * SEG;
    const half8* __restrict__ BL = reinterpret_cast<const half8*>(BLp) + (size_t)jb * SEG;
    const float* __restrict__ bp = lo.b[jb];
    float* __restrict__ Y = lo.y[jb];

    f32x16 acc[TJ];
#pragma unroll
    for (int jt = 0; jt < TJ; ++jt) {
        const float bv = bp ? bp[cg * TJ * 32 + jt * 32 + m] : 0.f;
#pragma unroll
        for (int r = 0; r < 16; ++r) acc[jt][r] = bv;
    }

    const int kf = h * 8;
    const float* pf = (kf < K1) ? (xr1 + kf) : (xr2 + (kf - K1));
    float4 xa = *reinterpret_cast<const float4*>(pf);
    float4 xb = *reinterpret_cast<const float4*>(pf + 4);

    for (int s = 0; s < K / 16; ++s) {
        const float xs[8] = {xa.x, xa.y, xa.z, xa.w, xb.x, xb.y, xb.z, xb.w};
        if (s + 1 < K / 16) {
            const int kn = (s + 1) * 16 + h * 8;
            const float* pn = (kn < K1) ? (xr1 + kn) : (xr2 + (kn - K1));
            xa = *reinterpret_cast<const float4*>(pn);
            xb = *reinterpret_cast<const float4*>(pn + 4);
        }
        half8 ah, al;
#pragma unroll
        for (int i = 0; i < 8; ++i) {
            const _Float16 hi = (_Float16)xs[i];
            ah[i] = hi;
            al[i] = (_Float16)(xs[i] - (float)hi);
        }
#pragma unroll
        for (int jt = 0; jt < TJ; ++jt) {
            const int fi = (s * TILES + cg * TJ + jt) * 64 + l;
            const half8 bh = BH[fi];
            const half8 bl = BL[fi];
            acc[jt] = __builtin_amdgcn_mfma_f32_32x32x16_f16(ah, bh, acc[jt], 0, 0, 0);
            acc[jt] = __builtin_amdgcn_mfma_f32_32x32x16_f16(al, bh, acc[jt], 0, 0, 0);
            acc[jt] = __builtin_amdgcn_mfma_f32_32x32x16_f16(ah, bl, acc[jt], 0, 0, 0);
        }
    }

    const int rbase = blockIdx.x * (32 * WR) + rg * 32;
#pragma unroll
    for (int jt = 0; jt < TJ; ++jt) {
        const int j = cg * TJ * 32 + jt * 32 + m;
#pragma unroll
        for (int r = 0; r < 16; ++r) {
            const int orow = rbase + (r & 3) + 8 * (r >> 2) + 4 * h;
            if (orow < N) {
                float v = acc[jt][r];
                if (RELU) v = fmaxf(v, 0.f);
                Y[(size_t)orow * LDY + j] = v;
            }
        }
    }
}

// --------------------------- fused GATv2 layer -----------------------------
__global__ void gat_fused_kernel(const float* __restrict__ fs, const float* __restrict__ fd,
                                 const float* __restrict__ attn,
                                 const int* __restrict__ row_off,
                                 const int* __restrict__ srcs,
                                 float* __restrict__ outp) {
    const int wv = threadIdx.x >> 6, l = threadIdx.x & 63;
    const int n = blockIdx.x * 4 + wv;
    if (n >= N_NODES) return;
    const int base = (l >> 5) * 128 + (l & 31) * 4;    // h*128 + d
    const float4 fdv = *reinterpret_cast<const float4*>(&fd[n * 256 + base]);
    const float4 av  = *reinterpret_cast<const float4*>(&attn[base]);
    const int s0 = row_off[n], s1 = row_off[n + 1];

    float m = -INFINITY, lsum = 0.f;
    float4 acc = {0.f, 0.f, 0.f, 0.f};
    float4 v0 = {0,0,0,0}, v1 = {0,0,0,0};
    if (s0 < s1)
        v0 = *reinterpret_cast<const float4*>(&fs[(size_t)srcs[s0] * 256 + base]);
    if (s0 + 1 < s1)
        v1 = *reinterpret_cast<const float4*>(&fs[(size_t)srcs[s0 + 1] * 256 + base]);
    for (int i = s0; i < s1; ++i) {
        const float4 vc = v0;
        v0 = v1;
        if (i + 2 < s1)                                  // depth-2 pipeline
            v1 = *reinterpret_cast<const float4*>(&fs[(size_t)srcs[i + 2] * 256 + base]);
        float p = lrelu(vc.x + fdv.x) * av.x;
        p = fmaf(lrelu(vc.y + fdv.y), av.y, p);
        p = fmaf(lrelu(vc.z + fdv.z), av.z, p);
        p = fmaf(lrelu(vc.w + fdv.w), av.w, p);
#pragma unroll
        for (int off = 1; off < 32; off <<= 1) p += __shfl_xor(p, off);
        const float mn = fmaxf(m, p);
        const float alpha = __expf(m - mn);              // first iter: exp(-inf)=0
        const float w = __expf(p - mn);
        lsum = fmaf(lsum, alpha, w);
        acc.x = fmaf(acc.x, alpha, w * vc.x);
        acc.y = fmaf(acc.y, alpha, w * vc.y);
        acc.z = fmaf(acc.z, alpha, w * vc.z);
        acc.w = fmaf(acc.w, alpha, w * vc.w);
        m = mn;
    }
    const float inv = (s1 > s0) ? 1.f / lsum : 0.f;
    float4 o;
    o.x = fmaxf(acc.x * inv, 0.f);
    o.y = fmaxf(acc.y * inv, 0.f);
    o.z = fmaxf(acc.z * inv, 0.f);
    o.w = fmaxf(acc.w * inv, 0.f);
    *reinterpret_cast<float4*>(&outp[n * 256 + base]) = o;
}

// ------------------------------ fused EdgeMLP v5 ---------------------------
// Block = 128 edges, 4 waves; wave = 32e x 256j. B quad-buffered in LDS
// (64 KB, barrier per 2 k-steps); x gather prefetched one PAIR ahead.
__global__ __launch_bounds__(256, 2) void edge_mlp5_kernel(
    const float* __restrict__ S, const float* __restrict__ Dn,
    const int* __restrict__ srcs, const int* __restrict__ eidx,
    const int* __restrict__ dstf,
    const _Float16* __restrict__ WpH, const _Float16* __restrict__ WpL,
    const float* __restrict__ b1, const float* __restrict__ w2,
    const float* __restrict__ b2, float* __restrict__ out) {
    __shared__ __align__(16) _Float16 Bs[2][2][8][2][512];   // 64 KB
    const int tid = threadIdx.x;
    const int wv  = tid >> 6, l = tid & 63;
    const int m   = l & 31, h = l >> 5;
    const int e0  = blockIdx.x * 128;
    const int slot = e0 + wv * 32 + m;
    const float* __restrict__ Srow = S  + (size_t)srcs[slot] * 512;
    const float* __restrict__ Drow = Dn + (size_t)dstf[eidx[slot]] * 512;

    f32x16 acc[8];
#pragma unroll
    for (int jt = 0; jt < 8; ++jt) {
        const float bv = b1[jt * 32 + m];
#pragma unroll
        for (int r = 0; r < 16; ++r) acc[jt][r] = bv;
    }

    // stage pair 0 (k-steps 0,1)
#pragma unroll
    for (int st = 0; st < 2; ++st)
#pragma unroll
        for (int c = 0; c < 4; ++c) {
            const int ch = wv * 4 + c, jt = ch >> 1, hb = ch & 1;
            const _Float16* sp = (hb ? WpL : WpH) + ((size_t)(st * 8 + jt) * 64 + l) * 8;
            *reinterpret_cast<float4*>(&Bs[0][st][jt][hb][l * 8]) =
                *reinterpret_cast<const float4*>(sp);
        }
    // x for pair 0
    float4 xc[2][4];
#pragma unroll
    for (int st = 0; st < 2; ++st) {
        const int ko = st * 16 + h * 8;
        xc[st][0] = *reinterpret_cast<const float4*>(Srow + ko);
        xc[st][1] = *reinterpret_cast<const float4*>(Srow + ko + 4);
        xc[st][2] = *reinterpret_cast<const float4*>(Drow + ko);
        xc[st][3] = *reinterpret_cast<const float4*>(Drow + ko + 4);
    }
    __syncthreads();

    for (int sp = 0; sp < 16; ++sp) {
        const int par = sp & 1;
        float4 xn[2][4];
        if (sp < 15) {                        // x prefetch for pair sp+1
#pragma unroll
            for (int st = 0; st < 2; ++st) {
                const int ko = (2 * (sp + 1) + st) * 16 + h * 8;
                xn[st][0] = *reinterpret_cast<const float4*>(Srow + ko);
                xn[st][1] = *reinterpret_cast<const float4*>(Srow + ko + 4);
                xn[st][2] = *reinterpret_cast<const float4*>(Drow + ko);
                xn[st][3] = *reinterpret_cast<const float4*>(Drow + ko + 4);
            }
        }
#pragma unroll
        for (int st = 0; st < 2; ++st) {
            float4 bst[4];
            if (sp < 15) {                    // B stage loads for pair sp+1, step st
#pragma unroll
                for (int c = 0; c < 4; ++c) {
                    const int ch = wv * 4 + c, jt = ch >> 1, hb = ch & 1;
                    const _Float16* sp2 = (hb ? WpL : WpH) +
                        ((size_t)((2 * (sp + 1) + st) * 8 + jt) * 64 + l) * 8;
                    bst[c] = *reinterpret_cast<const float4*>(sp2);
                }
            }
            const float4 A0 = xc[st][0], A1 = xc[st][1], A2 = xc[st][2], A3 = xc[st][3];
            const float xs[8] = {A0.x + A2.x, A0.y + A2.y, A0.z + A2.z, A0.w + A2.w,
                                 A1.x + A3.x, A1.y + A3.y, A1.z + A3.z, A1.w + A3.w};
            half8 ah, al;
#pragma unroll
            for (int i = 0; i < 8; ++i) {
                const float xv = fmaxf(xs[i], 0.f);
                const _Float16 hi = (_Float16)xv;
                ah[i] = hi;
                al[i] = (_Float16)(xv - (float)hi);
            }
#pragma unroll
            for (int jt = 0; jt < 8; ++jt) {
                const half8 bh = *reinterpret_cast<const half8*>(&Bs[par][st][jt][0][l * 8]);
                const half8 bl = *reinterpret_cast<const half8*>(&Bs[par][st][jt][1][l * 8]);
                acc[jt] = __builtin_amdgcn_mfma_f32_32x32x16_f16(ah, bh, acc[jt], 0, 0, 0);
                acc[jt] = __builtin_amdgcn_mfma_f32_32x32x16_f16(al, bh, acc[jt], 0, 0, 0);
                acc[jt] = __builtin_amdgcn_mfma_f32_32x32x16_f16(ah, bl, acc[jt], 0, 0, 0);
            }
            if (sp < 15) {
#pragma unroll
                for (int c = 0; c < 4; ++c) {
                    const int ch = wv * 4 + c, jt = ch >> 1, hb = ch & 1;
                    *reinterpret_cast<float4*>(&Bs[par ^ 1][st][jt][hb][l * 8]) = bst[c];
                }
            }
        }
        if (sp < 15) {
#pragma unroll
            for (int st = 0; st < 2; ++st)
#pragma unroll
                for (int q = 0; q < 4; ++q) xc[st][q] = xn[st][q];
        }
        __syncthreads();
    }

    // ---- layer-2 fold + 32-lane reduce + scatter store ----
    float part[16];
#pragma unroll
    for (int r = 0; r < 16; ++r) part[r] = 0.f;
#pragma unroll
    for (int jt = 0; jt < 8; ++jt) {
        const float w2v = w2[jt * 32 + m];
#pragma unroll
        for (int r = 0; r < 16; ++r)
            part[r] = fmaf(fmaxf(acc[jt][r], 0.f), w2v, part[r]);
    }
#pragma unroll
    for (int off = 1; off < 32; off <<= 1)
#pragma unroll
        for (int r = 0; r < 16; ++r) part[r] += __shfl_xor(part[r], off);
    if (m == 0) {
        const float b2v = b2[0];
#pragma unroll
        for (int r = 0; r < 16; ++r) {
            const int row = (r & 3) + 8 * (r >> 2) + 4 * h;
            out[eidx[e0 + wv * 32 + row]] = part[r] + b2v;
        }
    }
}

// ------------------------------ launch ------------------------------------
extern "C" void kernel_launch(void* const* d_in, const int* in_sizes, int n_in,
                              void* d_out, int out_size, void* d_ws, size_t ws_size,
                              hipStream_t stream) {
    (void)in_sizes; (void)n_in; (void)out_size; (void)ws_size;
    const float* x    = (const float*)d_in[0];
    const int*   src  = (const int*)d_in[1];
    const int*   dst  = (const int*)d_in[2];
    const float* nw0  = (const float*)d_in[3];
    const float* nb0  = (const float*)d_in[4];
    const float* nw1  = (const float*)d_in[5];
    const float* nb1  = (const float*)d_in[6];
    const float* g1ws = (const float*)d_in[7];
    const float* g1bs = (const float*)d_in[8];
    const float* g1wd = (const float*)d_in[9];
    const float* g1bd = (const float*)d_in[10];
    const float* g1a  = (const float*)d_in[11];
    const float* g2ws = (const float*)d_in[12];
    const float* g2bs = (const float*)d_in[13];
    const float* g2wd = (const float*)d_in[14];
    const float* g2bd = (const float*)d_in[15];
    const float* g2a  = (const float*)d_in[16];
    const float* ew0  = (const float*)d_in[17];
    const float* eb0  = (const float*)d_in[18];
    const float* ew1  = (const float*)d_in[19];
    const float* eb1  = (const float*)d_in[20];
    const float* ew2  = (const float*)d_in[21];
    const float* eb2  = (const float*)d_in[22];
    float* out = (float*)d_out;

    float* wsF = (float*)d_ws;
    float* h1  = wsF;                       // 20000*128
    float* g2o = wsF + 2560000;             // 20000*256
    float* fsb = wsF + 7680000;             // 20000*256
    float* fdb = wsF + 12800000;            // 20000*256
    float* g1o = wsF + 17920000;            // 20000*256
    float* Sb  = wsF + 7680000;             // 20000*512 overlays fsb+fdb (dead)
    float* Db  = wsF + 17920000;            // 20000*512 overlays g1o (dead) + fresh
    int* wsI     = (int*)(wsF + 28160000);
    int* row_off = wsI;                     // [0, 20016)
    int* cursor  = wsI + 20016;             // [20016, 40032)
    int* eidx    = wsI + 40032;             // [40032, 360032)
    int* srcs    = wsI + 360032;            // [360032, 680032)
    // ---- B-fragment pack region (tail) ----
    _Float16* pkH = (_Float16*)((char*)d_ws + 115361280);
    _Float16* pkL = pkH + (size_t)PACK_TOT * 8;

    // ---- CSR build ----
    hipMemsetAsync(cursor, 0, N_NODES * sizeof(int), stream);
    hist_kernel<<<1250, 256, 0, stream>>>(dst, cursor);
    scan_all_kernel<<<1, 1024, 0, stream>>>(cursor, row_off, cursor);
    scatter_kernel<<<1250, 256, 0, stream>>>(src, dst, cursor, eidx, srcs);

    // ---- merged weight prepack ----
    PackIn pin{ew1, g1ws, g1wd, g2ws, g2wd, ew0, nw0, nw1, pkH, pkL};
    prepack_all_kernel<<<(PACK_TOT + 255) / 256, 256, 0, stream>>>(pin);

    // ---- NodeMLP ----
    {   LinOut lo{{fsb, nullptr, nullptr, nullptr}, {nb0, nullptr, nullptr, nullptr}};
        mfma_linear2_kernel<64, 1, 1, 64, 64, 64, 128, true, 4, 0>
            <<<dim3(625, 1), 256, 0, stream>>>(x, x, pkH + OFF_N0 * 8, pkL + OFF_N0 * 8,
                                               lo, N_NODES); }
    {   LinOut lo{{h1, nullptr, nullptr, nullptr}, {nb1, nullptr, nullptr, nullptr}};
        mfma_linear2_kernel<128, 1, 1, 128, 128, 128, 128, true, 4, 0>
            <<<dim3(625, 1), 256, 0, stream>>>(fsb, fsb, pkH + OFF_N1 * 8, pkL + OFF_N1 * 8,
                                               lo, N_NODES); }

    // ---- GATv2 layer 1: fused fc (src|dst), then fused attention ----
    {   LinOut lo{{fsb, fdb, nullptr, nullptr}, {g1bs, g1bd, nullptr, nullptr}};
        mfma_linear2_kernel<64, 2, 1, 64, 64, 64, 256, false, 4, 2048>
            <<<dim3(625, 2), 256, 0, stream>>>(x, x, pkH + OFF_G1S * 8, pkL + OFF_G1S * 8,
                                               lo, N_NODES); }
    gat_fused_kernel<<<5000, 256, 0, stream>>>(fsb, fdb, g1a, row_off, srcs, g1o);

    // ---- GATv2 layer 2 ----
    {   LinOut lo{{fsb, fdb, nullptr, nullptr}, {g2bs, g2bd, nullptr, nullptr}};
        mfma_linear2_kernel<256, 2, 1, 256, 256, 256, 256, false, 4, 8192>
            <<<dim3(625, 2), 256, 0, stream>>>(g1o, g1o, pkH + OFF_G2S * 8, pkL + OFF_G2S * 8,
                                               lo, N_NODES); }
    gat_fused_kernel<<<5000, 256, 0, stream>>>(fsb, fdb, g2a, row_off, srcs, g2o);

    // ---- fused S|D precompute (EdgeMLP layer-0 decomposition) ----
    {   LinOut lo{{Sb, Sb + 256, Db, Db + 256}, {nullptr, nullptr, eb0, eb0 + 256}};
        mfma_linear2_kernel<384, 4, 2, 128, 128, 256, 512, false, 2, 12288>
            <<<dim3(313, 4), 256, 0, stream>>>(h1, g2o, pkH + OFF_SW0 * 8, pkL + OFF_SW0 * 8,
                                               lo, N_NODES); }

    // ---- fused EdgeMLP v5 ----
    edge_mlp5_kernel<<<N_EDGES / 128, 256, 0, stream>>>(Sb, Db, srcs, eidx, dst,
                                                        pkH + OFF_W1 * 8, pkL + OFF_W1 * 8,
                                                        eb1, ew2, eb2, out);
}

// Round 8
// 623.667 us; speedup vs baseline: 9.8666x; 1.0758x over previous
//
#include <hip/hip_runtime.h>
#include <hip/hip_bf16.h>

// ---------------------------------------------------------------------------
// EdgePredModel: NodeMLP + 2x GATv2 + EdgeMLP.
// R8: edge_mlp6 = mlp4 structure (per-step 2x8KB double buffer) with
//     2-product split (x full precision hi+lo, W1 fp16-rounded hi only):
//     halves B bytes through L1 and cuts MFMA 24->16 per wave-step.
//     Node side identical to R7 (3-product).
// ---------------------------------------------------------------------------
constexpr int N_NODES = 20000;
constexpr int N_EDGES = 320000;

typedef _Float16 half8 __attribute__((ext_vector_type(8)));
typedef float    f32x16 __attribute__((ext_vector_type(16)));

__device__ __forceinline__ float lrelu(float x) { return x > 0.f ? x : 0.2f * x; }

// ------------------------------ CSR build ---------------------------------
__global__ void hist_kernel(const int* __restrict__ dst, int* __restrict__ counts) {
    int e = blockIdx.x * 256 + threadIdx.x;
    if (e < N_EDGES) atomicAdd(&counts[dst[e]], 1);
}

// single-block exclusive scan of 20000 counts -> row_off, cursor
__global__ void scan_all_kernel(const int* __restrict__ counts,
                                int* __restrict__ row_off, int* __restrict__ cursor) {
    __shared__ int ps[1024];
    const int t = threadIdx.x;
    const int base = t * 20;
    int loc[20];
    int sum = 0;
#pragma unroll
    for (int i = 0; i < 20; ++i) {
        const int idx = base + i;
        const int v = (idx < N_NODES) ? counts[idx] : 0;
        loc[i] = sum;
        sum += v;
    }
    ps[t] = sum;
    __syncthreads();
    for (int off = 1; off < 1024; off <<= 1) {
        const int v = (t >= off) ? ps[t - off] : 0;
        __syncthreads();
        ps[t] += v;
        __syncthreads();
    }
    const int ex = ps[t] - sum;     // exclusive prefix of this thread's chunk
#pragma unroll
    for (int i = 0; i < 20; ++i) {
        const int idx = base + i;
        if (idx < N_NODES) {
            row_off[idx] = ex + loc[i];
            cursor[idx]  = ex + loc[i];
        }
    }
    if (t == 0) row_off[N_NODES] = N_EDGES;
}

__global__ void scatter_kernel(const int* __restrict__ src, const int* __restrict__ dst,
                               int* __restrict__ cursor, int* __restrict__ eidx,
                               int* __restrict__ srcs) {
    int e = blockIdx.x * 256 + threadIdx.x;
    if (e < N_EDGES) {
        int p = atomicAdd(&cursor[dst[e]], 1);
        eidx[p] = e;
        srcs[p] = src[e];
    }
}

// --------------------- merged W prepack into B-fragments -------------------
template <int K, int M>
__device__ __forceinline__ void pack_one(int idx, const float* __restrict__ W,
                                         int r1, int k1, int r2, int joff, int ldw,
                                         _Float16* __restrict__ H,
                                         _Float16* __restrict__ L) {
    const int l  = idx & 63;
    const int t  = (idx >> 6) % (M / 32);
    const int s  = (idx >> 6) / (M / 32);
    const int j  = joff + t * 32 + (l & 31);
    const int kb = s * 16 + (l >> 5) * 8;
    half8 vh, vl;
#pragma unroll
    for (int i = 0; i < 8; ++i) {
        const int k    = kb + i;
        const int rrow = (k < k1) ? (r1 + k) : (r2 + (k - k1));
        const float w  = W[(size_t)rrow * ldw + j];
        const _Float16 h = (_Float16)w;
        vh[i] = h;
        vl[i] = (_Float16)(w - (float)h);
    }
    reinterpret_cast<half8*>(H)[idx] = vh;
    reinterpret_cast<half8*>(L)[idx] = vl;
}

// segment offsets in half8 units
constexpr int OFF_W1  = 0;        // ew1  512x256 -> 16384
constexpr int OFF_G1S = 16384;    // g1ws  64x256 ->  2048
constexpr int OFF_G1D = 18432;
constexpr int OFF_G2S = 20480;    // g2ws 256x256 ->  8192
constexpr int OFF_G2D = 28672;
constexpr int OFF_SW0 = 36864;    // ew0-S cols 0-255   -> 12288
constexpr int OFF_SW1 = 49152;    // ew0-S cols 256-511
constexpr int OFF_DW0 = 61440;    // ew0-D cols 0-255
constexpr int OFF_DW1 = 73728;
constexpr int OFF_N0  = 86016;    // nw0 64x128 -> 1024
constexpr int OFF_N1  = 87040;    // nw1 128x128 -> 2048
constexpr int PACK_TOT = 89088;   // total half8

struct PackIn {
    const float *ew1, *g1ws, *g1wd, *g2ws, *g2wd, *ew0, *nw0, *nw1;
    _Float16 *H, *L;
};

__global__ void prepack_all_kernel(PackIn a) {
    const int idx = blockIdx.x * 256 + threadIdx.x;
    if (idx >= PACK_TOT) return;
    _Float16* H = a.H;
    _Float16* L = a.L;
    if (idx < OFF_G1S)
        pack_one<512, 256>(idx - OFF_W1, a.ew1, 0, 512, 0, 0, 256,
                           H + OFF_W1 * 8, L + OFF_W1 * 8);
    else if (idx < OFF_G1D)
        pack_one<64, 256>(idx - OFF_G1S, a.g1ws, 0, 64, 0, 0, 256,
                          H + OFF_G1S * 8, L + OFF_G1S * 8);
    else if (idx < OFF_G2S)
        pack_one<64, 256>(idx - OFF_G1D, a.g1wd, 0, 64, 0, 0, 256,
                          H + OFF_G1D * 8, L + OFF_G1D * 8);
    else if (idx < OFF_G2D)
        pack_one<256, 256>(idx - OFF_G2S, a.g2ws, 0, 256, 0, 0, 256,
                           H + OFF_G2S * 8, L + OFF_G2S * 8);
    else if (idx < OFF_SW0)
        pack_one<256, 256>(idx - OFF_G2D, a.g2wd, 0, 256, 0, 0, 256,
                           H + OFF_G2D * 8, L + OFF_G2D * 8);
    else if (idx < OFF_SW1)
        pack_one<384, 256>(idx - OFF_SW0, a.ew0, 0, 128, 256, 0, 512,
                           H + OFF_SW0 * 8, L + OFF_SW0 * 8);
    else if (idx < OFF_DW0)
        pack_one<384, 256>(idx - OFF_SW1, a.ew0, 0, 128, 256, 256, 512,
                           H + OFF_SW1 * 8, L + OFF_SW1 * 8);
    else if (idx < OFF_DW1)
        pack_one<384, 256>(idx - OFF_DW0, a.ew0, 128, 128, 512, 0, 512,
                           H + OFF_DW0 * 8, L + OFF_DW0 * 8);
    else if (idx < OFF_N0)
        pack_one<384, 256>(idx - OFF_DW1, a.ew0, 128, 128, 512, 256, 512,
                           H + OFF_DW1 * 8, L + OFF_DW1 * 8);
    else if (idx < OFF_N1)
        pack_one<64, 128>(idx - OFF_N0, a.nw0, 0, 64, 0, 0, 128,
                          H + OFF_N0 * 8, L + OFF_N0 * 8);
    else
        pack_one<128, 128>(idx - OFF_N1, a.nw1, 0, 128, 0, 0, 128,
                           H + OFF_N1 * 8, L + OFF_N1 * 8);
}

// ----------------------- split-fp16 MFMA node linear -----------------------
struct LinOut { float* y[4]; const float* b[4]; };

template <int K, int TJ, int WR, int K1, int LD1, int LD2, int LDY,
          bool RELU, int MINW, int SEG>
__global__ __launch_bounds__(256, MINW) void mfma_linear2_kernel(
    const float* __restrict__ X1, const float* __restrict__ X2,
    const _Float16* __restrict__ BHp, const _Float16* __restrict__ BLp,
    LinOut lo, int N) {
    constexpr int WC    = 4 / WR;
    constexpr int TILES = WC * TJ;
    const int jb  = blockIdx.y;
    const int tid = threadIdx.x;
    const int wv  = tid >> 6, l = tid & 63;
    const int rg  = (WR == 1) ? 0 : (wv & 1);
    const int cg  = (WR == 1) ? wv : (wv >> 1);
    const int m   = l & 31, h = l >> 5;
    const int row = blockIdx.x * (32 * WR) + rg * 32 + m;
    const int ar  = (row < N) ? row : (N - 1);
    const float* __restrict__ xr1 = X1 + (size_t)ar * LD1;
    const float* __restrict__ xr2 = X2 + (size_t)ar * LD2;
    const half8* __restrict__ BH = reinterpret_cast<const half8*>(BHp) + (size_t)jb * SEG;
    const half8* __restrict__ BL = reinterpret_cast<const half8*>(BLp) + (size_t)jb * SEG;
    const float* __restrict__ bp = lo.b[jb];
    float* __restrict__ Y = lo.y[jb];

    f32x16 acc[TJ];
#pragma unroll
    for (int jt = 0; jt < TJ; ++jt) {
        const float bv = bp ? bp[cg * TJ * 32 + jt * 32 + m] : 0.f;
#pragma unroll
        for (int r = 0; r < 16; ++r) acc[jt][r] = bv;
    }

    const int kf = h * 8;
    const float* pf = (kf < K1) ? (xr1 + kf) : (xr2 + (kf - K1));
    float4 xa = *reinterpret_cast<const float4*>(pf);
    float4 xb = *reinterpret_cast<const float4*>(pf + 4);

    for (int s = 0; s < K / 16; ++s) {
        const float xs[8] = {xa.x, xa.y, xa.z, xa.w, xb.x, xb.y, xb.z, xb.w};
        if (s + 1 < K / 16) {
            const int kn = (s + 1) * 16 + h * 8;
            const float* pn = (kn < K1) ? (xr1 + kn) : (xr2 + (kn - K1));
            xa = *reinterpret_cast<const float4*>(pn);
            xb = *reinterpret_cast<const float4*>(pn + 4);
        }
        half8 ah, al;
#pragma unroll
        for (int i = 0; i < 8; ++i) {
            const _Float16 hi = (_Float16)xs[i];
            ah[i] = hi;
            al[i] = (_Float16)(xs[i] - (float)hi);
        }
#pragma unroll
        for (int jt = 0; jt < TJ; ++jt) {
            const int fi = (s * TILES + cg * TJ + jt) * 64 + l;
            const half8 bh = BH[fi];
            const half8 bl = BL[fi];
            acc[jt] = __builtin_amdgcn_mfma_f32_32x32x16_f16(ah, bh, acc[jt], 0, 0, 0);
            acc[jt] = __builtin_amdgcn_mfma_f32_32x32x16_f16(al, bh, acc[jt], 0, 0, 0);
            acc[jt] = __builtin_amdgcn_mfma_f32_32x32x16_f16(ah, bl, acc[jt], 0, 0, 0);
        }
    }

    const int rbase = blockIdx.x * (32 * WR) + rg * 32;
#pragma unroll
    for (int jt = 0; jt < TJ; ++jt) {
        const int j = cg * TJ * 32 + jt * 32 + m;
#pragma unroll
        for (int r = 0; r < 16; ++r) {
            const int orow = rbase + (r & 3) + 8 * (r >> 2) + 4 * h;
            if (orow < N) {
                float v = acc[jt][r];
                if (RELU) v = fmaxf(v, 0.f);
                Y[(size_t)orow * LDY + j] = v;
            }
        }
    }
}

// --------------------------- fused GATv2 layer -----------------------------
__global__ void gat_fused_kernel(const float* __restrict__ fs, const float* __restrict__ fd,
                                 const float* __restrict__ attn,
                                 const int* __restrict__ row_off,
                                 const int* __restrict__ srcs,
                                 float* __restrict__ outp) {
    const int wv = threadIdx.x >> 6, l = threadIdx.x & 63;
    const int n = blockIdx.x * 4 + wv;
    if (n >= N_NODES) return;
    const int base = (l >> 5) * 128 + (l & 31) * 4;    // h*128 + d
    const float4 fdv = *reinterpret_cast<const float4*>(&fd[n * 256 + base]);
    const float4 av  = *reinterpret_cast<const float4*>(&attn[base]);
    const int s0 = row_off[n], s1 = row_off[n + 1];

    float m = -INFINITY, lsum = 0.f;
    float4 acc = {0.f, 0.f, 0.f, 0.f};
    float4 v0 = {0,0,0,0}, v1 = {0,0,0,0};
    if (s0 < s1)
        v0 = *reinterpret_cast<const float4*>(&fs[(size_t)srcs[s0] * 256 + base]);
    if (s0 + 1 < s1)
        v1 = *reinterpret_cast<const float4*>(&fs[(size_t)srcs[s0 + 1] * 256 + base]);
    for (int i = s0; i < s1; ++i) {
        const float4 vc = v0;
        v0 = v1;
        if (i + 2 < s1)                                  // depth-2 pipeline
            v1 = *reinterpret_cast<const float4*>(&fs[(size_t)srcs[i + 2] * 256 + base]);
        float p = lrelu(vc.x + fdv.x) * av.x;
        p = fmaf(lrelu(vc.y + fdv.y), av.y, p);
        p = fmaf(lrelu(vc.z + fdv.z), av.z, p);
        p = fmaf(lrelu(vc.w + fdv.w), av.w, p);
#pragma unroll
        for (int off = 1; off < 32; off <<= 1) p += __shfl_xor(p, off);
        const float mn = fmaxf(m, p);
        const float alpha = __expf(m - mn);              // first iter: exp(-inf)=0
        const float w = __expf(p - mn);
        lsum = fmaf(lsum, alpha, w);
        acc.x = fmaf(acc.x, alpha, w * vc.x);
        acc.y = fmaf(acc.y, alpha, w * vc.y);
        acc.z = fmaf(acc.z, alpha, w * vc.z);
        acc.w = fmaf(acc.w, alpha, w * vc.w);
        m = mn;
    }
    const float inv = (s1 > s0) ? 1.f / lsum : 0.f;
    float4 o;
    o.x = fmaxf(acc.x * inv, 0.f);
    o.y = fmaxf(acc.y * inv, 0.f);
    o.z = fmaxf(acc.z * inv, 0.f);
    o.w = fmaxf(acc.w * inv, 0.f);
    *reinterpret_cast<float4*>(&outp[n * 256 + base]) = o;
}

// ------------------------------ fused EdgeMLP v6 ---------------------------
// mlp4 structure, 2-product split: x = xh+xl full precision, W1 fp16 hi only.
// Block = 128 edges, 4 waves; wave = 32e x 256j. B hi staged per step into
// 2x8KB LDS double buffer (each wave stages 2 of 8 1-KB chunks). 16 MFMA
// per wave-step. Layer-2 folded; scatter store via eidx.
__global__ __launch_bounds__(256, 2) void edge_mlp6_kernel(
    const float* __restrict__ S, const float* __restrict__ Dn,
    const int* __restrict__ srcs, const int* __restrict__ eidx,
    const int* __restrict__ dstf,
    const _Float16* __restrict__ WpH,
    const float* __restrict__ b1, const float* __restrict__ w2,
    const float* __restrict__ b2, float* __restrict__ out) {
    __shared__ __align__(16) _Float16 Bs[2][8][512];   // 16 KB
    const int tid = threadIdx.x;
    const int wv  = tid >> 6, l = tid & 63;
    const int m   = l & 31, h = l >> 5;
    const int e0  = blockIdx.x * 128;
    const int slot = e0 + wv * 32 + m;
    const float* __restrict__ Srow = S  + (size_t)srcs[slot] * 512;
    const float* __restrict__ Drow = Dn + (size_t)dstf[eidx[slot]] * 512;

    f32x16 acc[8];
#pragma unroll
    for (int jt = 0; jt < 8; ++jt) {
        const float bv = b1[jt * 32 + m];
#pragma unroll
        for (int r = 0; r < 16; ++r) acc[jt][r] = bv;
    }

    // stage B(s=0) hi into buf 0: wave wv stages chunks 2wv, 2wv+1
#pragma unroll
    for (int c = 0; c < 2; ++c) {
        const int jt = wv * 2 + c;
        *reinterpret_cast<float4*>(&Bs[0][jt][l * 8]) =
            *reinterpret_cast<const float4*>(WpH + ((size_t)jt * 64 + l) * 8);
    }
    // x prefetch s=0
    float4 sa = *reinterpret_cast<const float4*>(Srow + h * 8);
    float4 sb = *reinterpret_cast<const float4*>(Srow + h * 8 + 4);
    float4 da = *reinterpret_cast<const float4*>(Drow + h * 8);
    float4 db = *reinterpret_cast<const float4*>(Drow + h * 8 + 4);
    __syncthreads();

    for (int s = 0; s < 32; ++s) {
        const int buf = s & 1;
        float4 bst[2];
        if (s < 31) {                        // B-hi stage loads for s+1
#pragma unroll
            for (int c = 0; c < 2; ++c) {
                const int jt = wv * 2 + c;
                bst[c] = *reinterpret_cast<const float4*>(
                    WpH + ((size_t)((s + 1) * 8 + jt) * 64 + l) * 8);
            }
        }
        const float xs[8] = {sa.x + da.x, sa.y + da.y, sa.z + da.z, sa.w + da.w,
                             sb.x + db.x, sb.y + db.y, sb.z + db.z, sb.w + db.w};
        if (s < 31) {                        // prefetch next x k-octet
            const int ko = (s + 1) * 16 + h * 8;
            sa = *reinterpret_cast<const float4*>(Srow + ko);
            sb = *reinterpret_cast<const float4*>(Srow + ko + 4);
            da = *reinterpret_cast<const float4*>(Drow + ko);
            db = *reinterpret_cast<const float4*>(Drow + ko + 4);
        }
        half8 ah, al;
#pragma unroll
        for (int i = 0; i < 8; ++i) {
            const float xv = fmaxf(xs[i], 0.f);
            const _Float16 hi = (_Float16)xv;
            ah[i] = hi;
            al[i] = (_Float16)(xv - (float)hi);
        }
#pragma unroll
        for (int jt = 0; jt < 8; ++jt) {
            const half8 bh = *reinterpret_cast<const half8*>(&Bs[buf][jt][l * 8]);
            acc[jt] = __builtin_amdgcn_mfma_f32_32x32x16_f16(ah, bh, acc[jt], 0, 0, 0);
            acc[jt] = __builtin_amdgcn_mfma_f32_32x32x16_f16(al, bh, acc[jt], 0, 0, 0);
        }
        if (s < 31) {
#pragma unroll
            for (int c = 0; c < 2; ++c) {
                const int jt = wv * 2 + c;
                *reinterpret_cast<float4*>(&Bs[buf ^ 1][jt][l * 8]) = bst[c];
            }
        }
        __syncthreads();
    }

    // ---- layer-2 fold + 32-lane reduce + scatter store ----
    float part[16];
#pragma unroll
    for (int r = 0; r < 16; ++r) part[r] = 0.f;
#pragma unroll
    for (int jt = 0; jt < 8; ++jt) {
        const float w2v = w2[jt * 32 + m];
#pragma unroll
        for (int r = 0; r < 16; ++r)
            part[r] = fmaf(fmaxf(acc[jt][r], 0.f), w2v, part[r]);
    }
#pragma unroll
    for (int off = 1; off < 32; off <<= 1)
#pragma unroll
        for (int r = 0; r < 16; ++r) part[r] += __shfl_xor(part[r], off);
    if (m == 0) {
        const float b2v = b2[0];
#pragma unroll
        for (int r = 0; r < 16; ++r) {
            const int row = (r & 3) + 8 * (r >> 2) + 4 * h;
            out[eidx[e0 + wv * 32 + row]] = part[r] + b2v;
        }
    }
}

// ------------------------------ launch ------------------------------------
extern "C" void kernel_launch(void* const* d_in, const int* in_sizes, int n_in,
                              void* d_out, int out_size, void* d_ws, size_t ws_size,
                              hipStream_t stream) {
    (void)in_sizes; (void)n_in; (void)out_size; (void)ws_size;
    const float* x    = (const float*)d_in[0];
    const int*   src  = (const int*)d_in[1];
    const int*   dst  = (const int*)d_in[2];
    const float* nw0  = (const float*)d_in[3];
    const float* nb0  = (const float*)d_in[4];
    const float* nw1  = (const float*)d_in[5];
    const float* nb1  = (const float*)d_in[6];
    const float* g1ws = (const float*)d_in[7];
    const float* g1bs = (const float*)d_in[8];
    const float* g1wd = (const float*)d_in[9];
    const float* g1bd = (const float*)d_in[10];
    const float* g1a  = (const float*)d_in[11];
    const float* g2ws = (const float*)d_in[12];
    const float* g2bs = (const float*)d_in[13];
    const float* g2wd = (const float*)d_in[14];
    const float* g2bd = (const float*)d_in[15];
    const float* g2a  = (const float*)d_in[16];
    const float* ew0  = (const float*)d_in[17];
    const float* eb0  = (const float*)d_in[18];
    const float* ew1  = (const float*)d_in[19];
    const float* eb1  = (const float*)d_in[20];
    const float* ew2  = (const float*)d_in[21];
    const float* eb2  = (const float*)d_in[22];
    float* out = (float*)d_out;

    float* wsF = (float*)d_ws;
    float* h1  = wsF;                       // 20000*128
    float* g2o = wsF + 2560000;             // 20000*256
    float* fsb = wsF + 7680000;             // 20000*256
    float* fdb = wsF + 12800000;            // 20000*256
    float* g1o = wsF + 17920000;            // 20000*256
    float* Sb  = wsF + 7680000;             // 20000*512 overlays fsb+fdb (dead)
    float* Db  = wsF + 17920000;            // 20000*512 overlays g1o (dead) + fresh
    int* wsI     = (int*)(wsF + 28160000);
    int* row_off = wsI;                     // [0, 20016)
    int* cursor  = wsI + 20016;             // [20016, 40032)
    int* eidx    = wsI + 40032;             // [40032, 360032)
    int* srcs    = wsI + 360032;            // [360032, 680032)
    // ---- B-fragment pack region (tail) ----
    _Float16* pkH = (_Float16*)((char*)d_ws + 115361280);
    _Float16* pkL = pkH + (size_t)PACK_TOT * 8;

    // ---- CSR build ----
    hipMemsetAsync(cursor, 0, N_NODES * sizeof(int), stream);
    hist_kernel<<<1250, 256, 0, stream>>>(dst, cursor);
    scan_all_kernel<<<1, 1024, 0, stream>>>(cursor, row_off, cursor);
    scatter_kernel<<<1250, 256, 0, stream>>>(src, dst, cursor, eidx, srcs);

    // ---- merged weight prepack ----
    PackIn pin{ew1, g1ws, g1wd, g2ws, g2wd, ew0, nw0, nw1, pkH, pkL};
    prepack_all_kernel<<<(PACK_TOT + 255) / 256, 256, 0, stream>>>(pin);

    // ---- NodeMLP ----
    {   LinOut lo{{fsb, nullptr, nullptr, nullptr}, {nb0, nullptr, nullptr, nullptr}};
        mfma_linear2_kernel<64, 1, 1, 64, 64, 64, 128, true, 4, 0>
            <<<dim3(625, 1), 256, 0, stream>>>(x, x, pkH + OFF_N0 * 8, pkL + OFF_N0 * 8,
                                               lo, N_NODES); }
    {   LinOut lo{{h1, nullptr, nullptr, nullptr}, {nb1, nullptr, nullptr, nullptr}};
        mfma_linear2_kernel<128, 1, 1, 128, 128, 128, 128, true, 4, 0>
            <<<dim3(625, 1), 256, 0, stream>>>(fsb, fsb, pkH + OFF_N1 * 8, pkL + OFF_N1 * 8,
                                               lo, N_NODES); }

    // ---- GATv2 layer 1: fused fc (src|dst), then fused attention ----
    {   LinOut lo{{fsb, fdb, nullptr, nullptr}, {g1bs, g1bd, nullptr, nullptr}};
        mfma_linear2_kernel<64, 2, 1, 64, 64, 64, 256, false, 4, 2048>
            <<<dim3(625, 2), 256, 0, stream>>>(x, x, pkH + OFF_G1S * 8, pkL + OFF_G1S * 8,
                                               lo, N_NODES); }
    gat_fused_kernel<<<5000, 256, 0, stream>>>(fsb, fdb, g1a, row_off, srcs, g1o);

    // ---- GATv2 layer 2 ----
    {   LinOut lo{{fsb, fdb, nullptr, nullptr}, {g2bs, g2bd, nullptr, nullptr}};
        mfma_linear2_kernel<256, 2, 1, 256, 256, 256, 256, false, 4, 8192>
            <<<dim3(625, 2), 256, 0, stream>>>(g1o, g1o, pkH + OFF_G2S * 8, pkL + OFF_G2S * 8,
                                               lo, N_NODES); }
    gat_fused_kernel<<<5000, 256, 0, stream>>>(fsb, fdb, g2a, row_off, srcs, g2o);

    // ---- fused S|D precompute (EdgeMLP layer-0 decomposition) ----
    {   LinOut lo{{Sb, Sb + 256, Db, Db + 256}, {nullptr, nullptr, eb0, eb0 + 256}};
        mfma_linear2_kernel<384, 4, 2, 128, 128, 256, 512, false, 2, 12288>
            <<<dim3(313, 4), 256, 0, stream>>>(h1, g2o, pkH + OFF_SW0 * 8, pkL + OFF_SW0 * 8,
                                               lo, N_NODES); }

    // ---- fused EdgeMLP v6 (2-product) ----
    edge_mlp6_kernel<<<N_EDGES / 128, 256, 0, stream>>>(Sb, Db, srcs, eidx, dst,
                                                        pkH + OFF_W1 * 8,
                                                        eb1, ew2, eb2, out);
}